// Round 2
// baseline (2209.381 us; speedup 1.0000x reference)
//
#include <hip/hip_runtime.h>
#include <hip/hip_bf16.h>

typedef unsigned short u16;
typedef unsigned int u32;
typedef __attribute__((ext_vector_type(8))) short short8_t;   // 8 bf16 (4 VGPRs)
typedef __attribute__((ext_vector_type(4))) float f32x4;

// ---- static problem config ----
#define NSUBJ 8
#define TOTAL 6848
#define MPAD  6912          // 54 * 128
#define DM    768
#define DI    1536
#define DS    16
#define DTR   48
#define DXP   80            // DTR + 2*DS
#define EPSN  1e-5f

__constant__ int d_OFF[NSUBJ + 1] = {0, 1024, 1920, 2688, 3712, 4224, 4864, 5824, 6848};

// ---- helpers ----
__device__ __forceinline__ float b2f(u16 u) {
    return __uint_as_float(((u32)u) << 16);
}
__device__ __forceinline__ u16 f2b(float f) {
    u32 u = __float_as_uint(f);
    u32 r = (u + 0x7FFFu + ((u >> 16) & 1u)) >> 16;
    return (u16)r;
}
// dual-path input load: inputs may be f32 (flag=1) or bf16 (flag=0)
__device__ __forceinline__ float ldin(const void* p, size_t i, int f32f) {
    return f32f ? ((const float*)p)[i] : b2f(((const u16*)p)[i]);
}
union U4 { uint4 v; u16 s[8]; };

__device__ __forceinline__ void unp8(uint4 v, float* o) {
    u32 a0 = v.x, a1 = v.y, a2 = v.z, a3 = v.w;
    o[0] = __uint_as_float(a0 << 16);  o[1] = __uint_as_float(a0 & 0xFFFF0000u);
    o[2] = __uint_as_float(a1 << 16);  o[3] = __uint_as_float(a1 & 0xFFFF0000u);
    o[4] = __uint_as_float(a2 << 16);  o[5] = __uint_as_float(a2 & 0xFFFF0000u);
    o[6] = __uint_as_float(a3 << 16);  o[7] = __uint_as_float(a3 & 0xFFFF0000u);
}

// block of 256 threads (4 waves) sums v across the block
__device__ __forceinline__ float block_sum(float v) {
    __shared__ float sbuf[8];
    __syncthreads();
    #pragma unroll
    for (int o = 32; o > 0; o >>= 1) v += __shfl_down(v, o, 64);
    const int lane = threadIdx.x & 63, w = threadIdx.x >> 6;
    if (lane == 0) sbuf[w] = v;
    __syncthreads();
    if (threadIdx.x == 0) sbuf[4] = sbuf[0] + sbuf[1] + sbuf[2] + sbuf[3];
    __syncthreads();
    return sbuf[4];
}

// ---- dtype detection: f32 data read as u16 has ~44% "huge-exponent" low halves ----
__global__ void detect_dtype(const u16* __restrict__ probe, int* __restrict__ flag) {
    const int lane = threadIdx.x;
    int cnt = 0;
    for (int i = 0; i < 32; ++i) {
        const u16 v = probe[lane * 32 + i];
        if (((v >> 7) & 0xFF) >= 0x90) cnt++;
    }
    #pragma unroll
    for (int o = 32; o > 0; o >>= 1) cnt += __shfl_down(cnt, o, 64);
    if (lane == 0) *flag = (cnt > 64) ? 1 : 0;
}

// ---- f32 -> bf16 weight conversion (no-op when inputs already bf16) ----
__global__ void cvt_f2b(const float* __restrict__ src, u16* __restrict__ dst, int n,
                        const int* __restrict__ flagp) {
    if (*flagp == 0) return;
    const int i = blockIdx.x * 256 + threadIdx.x;
    if (i < n) dst[i] = f2b(src[i]);
}

// ---- kernel 1: embedding gather + rmsnorm(in_norm_w) -> h (f32, compact layout) ----
__global__ void embed_rms(const int* __restrict__ tokens, const void* __restrict__ embed,
                          const void* __restrict__ w, float* __restrict__ h,
                          const int* __restrict__ flagp) {
    const int f32f = *flagp;
    const int f = blockIdx.x;
    const int tid = threadIdx.x;
    const int row = tokens[f];
    float v[3]; float ss = 0.f;
    #pragma unroll
    for (int i = 0; i < 3; ++i) {
        v[i] = ldin(embed, (size_t)row * DM + tid + 256 * i, f32f);
        ss += v[i] * v[i];
    }
    const float tot = block_sum(ss);
    const float rs = rsqrtf(tot * (1.f / DM) + EPSN);
    #pragma unroll
    for (int i = 0; i < 3; ++i)
        h[(size_t)f * DM + tid + 256 * i] = v[i] * rs * ldin(w, tid + 256 * i, f32f);
}

// ---- kernel 2: rmsnorm(h f32, w) -> normed bf16 ----
__global__ void rms_f2b(const float* __restrict__ h, const void* __restrict__ w, int woff,
                        u16* __restrict__ out, const int* __restrict__ flagp) {
    const int f32f = *flagp;
    const int f = blockIdx.x;
    const int tid = threadIdx.x;
    float v[3]; float ss = 0.f;
    #pragma unroll
    for (int i = 0; i < 3; ++i) { v[i] = h[(size_t)f * DM + tid + 256 * i]; ss += v[i] * v[i]; }
    const float tot = block_sum(ss);
    const float rs = rsqrtf(tot * (1.f / DM) + EPSN);
    #pragma unroll
    for (int i = 0; i < 3; ++i)
        out[(size_t)f * DM + tid + 256 * i] =
            f2b(v[i] * rs * ldin(w, woff + tid + 256 * i, f32f));
}

// ---- MFMA GEMM: C[M,N] (+epi) = A[M,K](lda) * B[N,K](ldb)^T, bf16 in, f32 acc ----
// EPI: 0 = store bf16; 1 = softplus(acc + bias[n]) store bf16; 2 = C(f32) += acc
#define TM 128
#define TN 128
#define BK 32
#define BKP 40   // padded LDS leading dim (bf16 elems): 80B rows -> conflict-free b128 reads

template <int EPI>
__global__ void gemm_bt(const u16* __restrict__ A, const u16* __restrict__ Borig,
                        const u16* __restrict__ Bcv, void* __restrict__ Cv,
                        const void* __restrict__ bias, int bias_off,
                        const int* __restrict__ flagp,
                        int M, int N, int K, int lda, int ldb, int ldc) {
    __shared__ u16 sA[TM * BKP];
    __shared__ u16 sB[TN * BKP];
    const int f32f = *flagp;
    const u16* __restrict__ B = f32f ? Bcv : Borig;
    const int tid = threadIdx.x;
    const int bm = blockIdx.x * TM;
    const int bn = blockIdx.y * TN;
    const int lane = tid & 63, w = tid >> 6;
    const int wm = (w >> 1) * 64, wn = (w & 1) * 64;
    const int lr = lane & 15;
    const int kg = (lane >> 4) * 8;

    f32x4 acc[4][4];
    #pragma unroll
    for (int i = 0; i < 4; ++i)
        #pragma unroll
        for (int j = 0; j < 4; ++j)
            acc[i][j] = (f32x4){0.f, 0.f, 0.f, 0.f};

    const int sr = tid >> 1;            // staging row 0..127 (2 threads/row)
    const int skc = (tid & 1) * 16;     // staging k-offset 0 or 16

    for (int k0 = 0; k0 < K; k0 += BK) {
        __syncthreads();
        // stage A tile (M rows always valid: M is a multiple of 128)
        {
            uint4 v0 = {0,0,0,0}, v1 = {0,0,0,0};
            const size_t go = (size_t)(bm + sr) * lda + (k0 + skc);
            if (k0 + skc < K)     v0 = *(const uint4*)(A + go);
            if (k0 + skc + 8 < K) v1 = *(const uint4*)(A + go + 8);
            *(uint4*)&sA[sr * BKP + skc]     = v0;
            *(uint4*)&sA[sr * BKP + skc + 8] = v1;
        }
        // stage B tile (guard n < N and k < K)
        {
            uint4 v0 = {0,0,0,0}, v1 = {0,0,0,0};
            const int gn = bn + sr;
            if (gn < N) {
                const size_t go = (size_t)gn * ldb + (k0 + skc);
                if (k0 + skc < K)     v0 = *(const uint4*)(B + go);
                if (k0 + skc + 8 < K) v1 = *(const uint4*)(B + go + 8);
            }
            *(uint4*)&sB[sr * BKP + skc]     = v0;
            *(uint4*)&sB[sr * BKP + skc + 8] = v1;
        }
        __syncthreads();

        short8_t af[4], bfr[4];
        #pragma unroll
        for (int i = 0; i < 4; ++i)
            af[i] = *(const short8_t*)&sA[(wm + i * 16 + lr) * BKP + kg];
        #pragma unroll
        for (int j = 0; j < 4; ++j)
            bfr[j] = *(const short8_t*)&sB[(wn + j * 16 + lr) * BKP + kg];
        #pragma unroll
        for (int i = 0; i < 4; ++i)
            #pragma unroll
            for (int j = 0; j < 4; ++j)
                acc[i][j] = __builtin_amdgcn_mfma_f32_16x16x32_bf16(af[i], bfr[j], acc[i][j], 0, 0, 0);
    }

    // epilogue: C/D layout col=lane&15, row=(lane>>4)*4 + reg   [verified m89/m91]
    const int cr = (lane >> 4) * 4;
    const int cc = lane & 15;
    #pragma unroll
    for (int i = 0; i < 4; ++i) {
        const int gm0 = bm + wm + i * 16 + cr;
        #pragma unroll
        for (int j = 0; j < 4; ++j) {
            const int gn = bn + wn + j * 16 + cc;
            if (gn < N) {
                float bval = 0.f;
                if (EPI == 1) bval = ldin(bias, (size_t)(bias_off + gn), f32f);
                #pragma unroll
                for (int r = 0; r < 4; ++r) {
                    float v = acc[i][j][r];
                    const size_t idx = (size_t)(gm0 + r) * ldc + gn;
                    if (EPI == 0) {
                        ((u16*)Cv)[idx] = f2b(v);
                    } else if (EPI == 1) {
                        v += bval;
                        v = (v > 20.f) ? v : log1pf(__expf(v));
                        ((u16*)Cv)[idx] = f2b(v);
                    } else {
                        ((float*)Cv)[idx] += v;
                    }
                }
            }
        }
    }
}

// ---- kernel: causal depthwise conv(K=4) + bias + silu ----
// reads x-half of xz [MPAD,3072] (internal bf16), writes xc [MPAD,1536]
__global__ void conv_silu(const u16* __restrict__ xz, const void* __restrict__ cw, int cwoff,
                          const void* __restrict__ cb, int cboff, u16* __restrict__ xc,
                          const int* __restrict__ flagp) {
    const int f32f = *flagp;
    const int gid = blockIdx.x * 256 + threadIdx.x;
    if (gid >= TOTAL * (DI / 8)) return;
    const int f = gid / (DI / 8);
    const int cg = gid % (DI / 8);
    const int c = cg * 8;
    int s = 0;
    while (f >= d_OFF[s + 1]) s++;
    const int t = f - d_OFF[s];

    float acc[8];
    #pragma unroll
    for (int i = 0; i < 8; ++i) acc[i] = ldin(cb, (size_t)cboff + c + i, f32f);
    float wv[32];
    #pragma unroll
    for (int i = 0; i < 32; ++i) wv[i] = ldin(cw, (size_t)cwoff + (size_t)c * 4 + i, f32f);

    #pragma unroll
    for (int j = 0; j < 4; ++j) {
        const int tj = t - 3 + j;
        if (tj >= 0) {
            U4 xv; xv.v = *(const uint4*)(xz + (size_t)(f - 3 + j) * (2 * DI) + c);
            #pragma unroll
            for (int i = 0; i < 8; ++i) acc[i] += b2f(xv.s[i]) * wv[i * 4 + j];
        }
    }
    U4 o;
    #pragma unroll
    for (int i = 0; i < 8; ++i) {
        const float a = acc[i];
        o.s[i] = f2b(a / (1.f + __expf(-a)));
    }
    *(uint4*)(xc + (size_t)f * DI + c) = o.v;
}

// ---- selective scan: one wave per (subject, 64-channel group), state in regs ----
__global__ __launch_bounds__(64)
void scan_kernel(const u16* __restrict__ xc, const u16* __restrict__ dt,
                 const u16* __restrict__ xz, const u16* __restrict__ dbl,
                 const void* __restrict__ A_log, int aoff,
                 const void* __restrict__ Dp, int doff,
                 u16* __restrict__ y, const int* __restrict__ flagp) {
    const int f32f = *flagp;
    const int s = blockIdx.x / (DI / 64);
    const int cg = blockIdx.x % (DI / 64);
    const int lane = threadIdx.x;
    const int c = cg * 64 + lane;
    const int off = d_OFF[s];
    const int L = d_OFF[s + 1] - off;

    float A[16];
    #pragma unroll
    for (int n = 0; n < 16; ++n)
        A[n] = -__expf(ldin(A_log, (size_t)aoff + (size_t)c * DS + n, f32f));
    const float Dv = ldin(Dp, (size_t)doff + c, f32f);
    float h[16];
    #pragma unroll
    for (int n = 0; n < 16; ++n) h[n] = 0.f;

    // prefetch t = 0
    size_t p = off;
    u16 xu = xc[p * DI + c];
    u16 du = dt[p * DI + c];
    u16 zu = xz[p * (2 * DI) + DI + c];
    uint4 b0 = *(const uint4*)(dbl + p * DXP + 48);
    uint4 b1 = *(const uint4*)(dbl + p * DXP + 56);
    uint4 b2 = *(const uint4*)(dbl + p * DXP + 64);
    uint4 b3 = *(const uint4*)(dbl + p * DXP + 72);

    for (int t = 0; t < L; ++t) {
        const size_t pc = (size_t)off + t;
        const float x = b2f(xu), dtv = b2f(du), z = b2f(zu);
        float Bv[16], Cvv[16];
        unp8(b0, Bv);  unp8(b1, Bv + 8);
        unp8(b2, Cvv); unp8(b3, Cvv + 8);
        if (t + 1 < L) {  // issue next-step loads before the serial math
            const size_t pn = pc + 1;
            xu = xc[pn * DI + c];
            du = dt[pn * DI + c];
            zu = xz[pn * (2 * DI) + DI + c];
            b0 = *(const uint4*)(dbl + pn * DXP + 48);
            b1 = *(const uint4*)(dbl + pn * DXP + 56);
            b2 = *(const uint4*)(dbl + pn * DXP + 64);
            b3 = *(const uint4*)(dbl + pn * DXP + 72);
        }
        float acc = 0.f;
        const float dtx = dtv * x;
        #pragma unroll
        for (int n = 0; n < 16; ++n) {
            const float dA = __expf(dtv * A[n]);
            h[n] = dA * h[n] + dtx * Bv[n];
            acc += h[n] * Cvv[n];
        }
        const float sig = 1.f / (1.f + __expf(-z));
        y[pc * DI + c] = f2b((acc + x * Dv) * (z * sig));
    }
}

// ---- final: rmsnorm(h, norm_f_w) then rmsnorm(., out_norm_w) -> d_out ----
__global__ void final_norm(const float* __restrict__ h, const void* __restrict__ wf,
                           const void* __restrict__ wo, void* __restrict__ out,
                           const int* __restrict__ flagp) {
    const int f32f = *flagp;
    const int f = blockIdx.x;
    const int tid = threadIdx.x;
    float v[3]; float ss = 0.f;
    #pragma unroll
    for (int i = 0; i < 3; ++i) { v[i] = h[(size_t)f * DM + tid + 256 * i]; ss += v[i] * v[i]; }
    float tot = block_sum(ss);
    float rs = rsqrtf(tot * (1.f / DM) + EPSN);
    float ss2 = 0.f;
    #pragma unroll
    for (int i = 0; i < 3; ++i) {
        v[i] = v[i] * rs * ldin(wf, tid + 256 * i, f32f);
        ss2 += v[i] * v[i];
    }
    tot = block_sum(ss2);
    rs = rsqrtf(tot * (1.f / DM) + EPSN);
    #pragma unroll
    for (int i = 0; i < 3; ++i) {
        const float r = v[i] * rs * ldin(wo, tid + 256 * i, f32f);
        const size_t idx = (size_t)f * DM + tid + 256 * i;
        if (f32f) ((float*)out)[idx] = r;
        else      ((u16*)out)[idx] = f2b(r);
    }
}

extern "C" void kernel_launch(void* const* d_in, const int* in_sizes, int n_in,
                              void* d_out, int out_size, void* d_ws, size_t ws_size,
                              hipStream_t stream) {
    const int*  tokens     = (const int*)d_in[0];
    const void* embed      = d_in[1];
    const void* in_norm_w  = d_in[2];
    const void* out_norm_w = d_in[3];
    const void* norm_w     = d_in[4];
    const void* in_proj_w  = d_in[5];
    const void* conv_w     = d_in[6];
    const void* conv_b     = d_in[7];
    const void* x_proj_w   = d_in[8];
    const void* dt_proj_w  = d_in[9];
    const void* dt_proj_b  = d_in[10];
    const void* A_log      = d_in[11];
    const void* D_param    = d_in[12];
    const void* out_proj_w = d_in[13];
    const void* norm_f_w   = d_in[14];

    // workspace layout (byte offsets, all 16B aligned)
    char* ws = (char*)d_ws;
    float* h    = (float*)(ws);                     // MPAD*768*4  = 21,233,664
    u16* normed = (u16*)(ws + 21233664);            // MPAD*768*2
    u16* xz     = (u16*)(ws + 31850496);            // MPAD*3072*2
    u16* xcb    = (u16*)(ws + 74317824);            // MPAD*1536*2
    u16* dbl    = (u16*)(ws + 95551488);            // MPAD*80*2
    u16* dtb    = (u16*)(ws + 96657408);            // MPAD*1536*2
    u16* yb     = (u16*)(ws + 117891072);           // MPAD*1536*2
    u16* w_ip   = (u16*)(ws + 139124736);           // 2*3072*768  bf16
    u16* w_op   = (u16*)(ws + 148561920);           // 2*768*1536  bf16
    u16* w_xp   = (u16*)(ws + 153280512);           // 2*80*1536   bf16
    u16* w_dt   = (u16*)(ws + 153772032);           // 2*1536*48   bf16
    int* flag   = (int*)(ws + 154066944);
    // total ~154.07 MB

    detect_dtype<<<1, 64, 0, stream>>>((const u16*)embed, flag);

    cvt_f2b<<<(2 * 2 * DI * DM + 255) / 256, 256, 0, stream>>>((const float*)in_proj_w,  w_ip, 2 * 2 * DI * DM, flag);
    cvt_f2b<<<(2 * DM * DI + 255) / 256, 256, 0, stream>>>((const float*)out_proj_w, w_op, 2 * DM * DI, flag);
    cvt_f2b<<<(2 * DXP * DI + 255) / 256, 256, 0, stream>>>((const float*)x_proj_w,  w_xp, 2 * DXP * DI, flag);
    cvt_f2b<<<(2 * DI * DTR + 255) / 256, 256, 0, stream>>>((const float*)dt_proj_w, w_dt, 2 * DI * DTR, flag);

    embed_rms<<<TOTAL, 256, 0, stream>>>(tokens, embed, in_norm_w, h, flag);

    for (int l = 0; l < 2; ++l) {
        rms_f2b<<<TOTAL, 256, 0, stream>>>(h, norm_w, l * DM, normed, flag);
        // in_proj: [MPAD,768] x [3072,768]^T -> xz [MPAD,3072]
        gemm_bt<0><<<dim3(MPAD / TM, 3072 / TN), 256, 0, stream>>>(
            normed, (const u16*)in_proj_w + (size_t)l * 2 * DI * DM,
            w_ip + (size_t)l * 2 * DI * DM, xz, nullptr, 0, flag,
            MPAD, 2 * DI, DM, DM, DM, 2 * DI);
        conv_silu<<<(TOTAL * (DI / 8)) / 256, 256, 0, stream>>>(
            xz, conv_w, l * DI * 4, conv_b, l * DI, xcb, flag);
        // x_proj: [MPAD,1536] x [80,1536]^T -> dbl [MPAD,80]
        gemm_bt<0><<<dim3(MPAD / TM, 1), 256, 0, stream>>>(
            xcb, (const u16*)x_proj_w + (size_t)l * DXP * DI,
            w_xp + (size_t)l * DXP * DI, dbl, nullptr, 0, flag,
            MPAD, DXP, DI, DI, DI, DXP);
        // dt_proj: [MPAD,48](lda=80) x [1536,48]^T -> softplus(+b) -> dtb [MPAD,1536]
        gemm_bt<1><<<dim3(MPAD / TM, DI / TN), 256, 0, stream>>>(
            dbl, (const u16*)dt_proj_w + (size_t)l * DI * DTR,
            w_dt + (size_t)l * DI * DTR, dtb, dt_proj_b, l * DI, flag,
            MPAD, DI, DTR, DXP, DTR, DI);
        scan_kernel<<<NSUBJ * (DI / 64), 64, 0, stream>>>(
            xcb, dtb, xz, dbl, A_log, l * DI * DS, D_param, l * DI, yb, flag);
        // out_proj: [MPAD,1536] x [768,1536]^T -> h += (residual)
        gemm_bt<2><<<dim3(MPAD / TM, DM / TN), 256, 0, stream>>>(
            yb, (const u16*)out_proj_w + (size_t)l * DM * DI,
            w_op + (size_t)l * DM * DI, h, nullptr, 0, flag,
            MPAD, DM, DI, DI, DI, DM);
    }

    final_norm<<<TOTAL, 256, 0, stream>>>(h, norm_f_w, out_norm_w, d_out, flag);
}

// Round 3
// 1116.147 us; speedup vs baseline: 1.9795x; 1.9795x over previous
//
#include <hip/hip_runtime.h>
#include <hip/hip_bf16.h>

typedef unsigned short u16;
typedef unsigned int u32;
typedef __attribute__((ext_vector_type(8))) short short8_t;   // 8 bf16 (4 VGPRs)
typedef __attribute__((ext_vector_type(4))) float f32x4;

// ---- static problem config ----
#define NSUBJ 8
#define TOTAL 6848
#define MPAD  6912          // 54 * 128
#define DM    768
#define DI    1536
#define DS    16
#define DTR   48
#define DXP   80            // DTR + 2*DS
#define EPSN  1e-5f
#define NCHUNK 107          // TOTAL / 64; every subject length & offset divisible by 64

__constant__ int d_OFF[NSUBJ + 1] = {0, 1024, 1920, 2688, 3712, 4224, 4864, 5824, 6848};

// ---- helpers ----
__device__ __forceinline__ float b2f(u16 u) {
    return __uint_as_float(((u32)u) << 16);
}
__device__ __forceinline__ u16 f2b(float f) {
    u32 u = __float_as_uint(f);
    u32 r = (u + 0x7FFFu + ((u >> 16) & 1u)) >> 16;
    return (u16)r;
}
// dual-path input load: inputs may be f32 (flag=1) or bf16 (flag=0)
__device__ __forceinline__ float ldin(const void* p, size_t i, int f32f) {
    return f32f ? ((const float*)p)[i] : b2f(((const u16*)p)[i]);
}
union U4 { uint4 v; u16 s[8]; };

__device__ __forceinline__ void unp8(uint4 v, float* o) {
    u32 a0 = v.x, a1 = v.y, a2 = v.z, a3 = v.w;
    o[0] = __uint_as_float(a0 << 16);  o[1] = __uint_as_float(a0 & 0xFFFF0000u);
    o[2] = __uint_as_float(a1 << 16);  o[3] = __uint_as_float(a1 & 0xFFFF0000u);
    o[4] = __uint_as_float(a2 << 16);  o[5] = __uint_as_float(a2 & 0xFFFF0000u);
    o[6] = __uint_as_float(a3 << 16);  o[7] = __uint_as_float(a3 & 0xFFFF0000u);
}

// block of 256 threads (4 waves) sums v across the block
__device__ __forceinline__ float block_sum(float v) {
    __shared__ float sbuf[8];
    __syncthreads();
    #pragma unroll
    for (int o = 32; o > 0; o >>= 1) v += __shfl_down(v, o, 64);
    const int lane = threadIdx.x & 63, w = threadIdx.x >> 6;
    if (lane == 0) sbuf[w] = v;
    __syncthreads();
    if (threadIdx.x == 0) sbuf[4] = sbuf[0] + sbuf[1] + sbuf[2] + sbuf[3];
    __syncthreads();
    return sbuf[4];
}

// ---- dtype detection: f32 data read as u16 has ~44% "huge-exponent" low halves ----
__global__ void detect_dtype(const u16* __restrict__ probe, int* __restrict__ flag) {
    const int lane = threadIdx.x;
    int cnt = 0;
    for (int i = 0; i < 32; ++i) {
        const u16 v = probe[lane * 32 + i];
        if (((v >> 7) & 0xFF) >= 0x90) cnt++;
    }
    #pragma unroll
    for (int o = 32; o > 0; o >>= 1) cnt += __shfl_down(cnt, o, 64);
    if (lane == 0) *flag = (cnt > 64) ? 1 : 0;
}

// ---- f32 -> bf16 weight conversion (no-op when inputs already bf16) ----
__global__ void cvt_f2b(const float* __restrict__ src, u16* __restrict__ dst, int n,
                        const int* __restrict__ flagp) {
    if (*flagp == 0) return;
    const int i = blockIdx.x * 256 + threadIdx.x;
    if (i < n) dst[i] = f2b(src[i]);
}

// ---- kernel 1: embedding gather + rmsnorm(in_norm_w) -> h (f32, compact layout) ----
__global__ void embed_rms(const int* __restrict__ tokens, const void* __restrict__ embed,
                          const void* __restrict__ w, float* __restrict__ h,
                          const int* __restrict__ flagp) {
    const int f32f = *flagp;
    const int f = blockIdx.x;
    const int tid = threadIdx.x;
    const int row = tokens[f];
    float v[3]; float ss = 0.f;
    #pragma unroll
    for (int i = 0; i < 3; ++i) {
        v[i] = ldin(embed, (size_t)row * DM + tid + 256 * i, f32f);
        ss += v[i] * v[i];
    }
    const float tot = block_sum(ss);
    const float rs = rsqrtf(tot * (1.f / DM) + EPSN);
    #pragma unroll
    for (int i = 0; i < 3; ++i)
        h[(size_t)f * DM + tid + 256 * i] = v[i] * rs * ldin(w, tid + 256 * i, f32f);
}

// ---- kernel 2: rmsnorm(h f32, w) -> normed bf16 ----
__global__ void rms_f2b(const float* __restrict__ h, const void* __restrict__ w, int woff,
                        u16* __restrict__ out, const int* __restrict__ flagp) {
    const int f32f = *flagp;
    const int f = blockIdx.x;
    const int tid = threadIdx.x;
    float v[3]; float ss = 0.f;
    #pragma unroll
    for (int i = 0; i < 3; ++i) { v[i] = h[(size_t)f * DM + tid + 256 * i]; ss += v[i] * v[i]; }
    const float tot = block_sum(ss);
    const float rs = rsqrtf(tot * (1.f / DM) + EPSN);
    #pragma unroll
    for (int i = 0; i < 3; ++i)
        out[(size_t)f * DM + tid + 256 * i] =
            f2b(v[i] * rs * ldin(w, woff + tid + 256 * i, f32f));
}

// ---- MFMA GEMM: C[M,N] (+epi) = A[M,K](lda) * B[N,K](ldb)^T, bf16 in, f32 acc ----
// EPI: 0 = store bf16; 1 = softplus(acc + bias[n]) store bf16; 2 = C(f32) += acc
#define TM 128
#define TN 128
#define BK 32
#define BKP 40   // padded LDS leading dim (bf16 elems): 80B rows -> conflict-free b128 reads

template <int EPI>
__global__ void gemm_bt(const u16* __restrict__ A, const u16* __restrict__ Borig,
                        const u16* __restrict__ Bcv, void* __restrict__ Cv,
                        const void* __restrict__ bias, int bias_off,
                        const int* __restrict__ flagp,
                        int M, int N, int K, int lda, int ldb, int ldc) {
    __shared__ u16 sA[TM * BKP];
    __shared__ u16 sB[TN * BKP];
    const int f32f = *flagp;
    const u16* __restrict__ B = f32f ? Bcv : Borig;
    const int tid = threadIdx.x;
    const int bm = blockIdx.x * TM;
    const int bn = blockIdx.y * TN;
    const int lane = tid & 63, w = tid >> 6;
    const int wm = (w >> 1) * 64, wn = (w & 1) * 64;
    const int lr = lane & 15;
    const int kg = (lane >> 4) * 8;

    f32x4 acc[4][4];
    #pragma unroll
    for (int i = 0; i < 4; ++i)
        #pragma unroll
        for (int j = 0; j < 4; ++j)
            acc[i][j] = (f32x4){0.f, 0.f, 0.f, 0.f};

    const int sr = tid >> 1;            // staging row 0..127 (2 threads/row)
    const int skc = (tid & 1) * 16;     // staging k-offset 0 or 16

    for (int k0 = 0; k0 < K; k0 += BK) {
        __syncthreads();
        // stage A tile (M rows always valid: M is a multiple of 128)
        {
            uint4 v0 = {0,0,0,0}, v1 = {0,0,0,0};
            const size_t go = (size_t)(bm + sr) * lda + (k0 + skc);
            if (k0 + skc < K)     v0 = *(const uint4*)(A + go);
            if (k0 + skc + 8 < K) v1 = *(const uint4*)(A + go + 8);
            *(uint4*)&sA[sr * BKP + skc]     = v0;
            *(uint4*)&sA[sr * BKP + skc + 8] = v1;
        }
        // stage B tile (guard n < N and k < K)
        {
            uint4 v0 = {0,0,0,0}, v1 = {0,0,0,0};
            const int gn = bn + sr;
            if (gn < N) {
                const size_t go = (size_t)gn * ldb + (k0 + skc);
                if (k0 + skc < K)     v0 = *(const uint4*)(B + go);
                if (k0 + skc + 8 < K) v1 = *(const uint4*)(B + go + 8);
            }
            *(uint4*)&sB[sr * BKP + skc]     = v0;
            *(uint4*)&sB[sr * BKP + skc + 8] = v1;
        }
        __syncthreads();

        short8_t af[4], bfr[4];
        #pragma unroll
        for (int i = 0; i < 4; ++i)
            af[i] = *(const short8_t*)&sA[(wm + i * 16 + lr) * BKP + kg];
        #pragma unroll
        for (int j = 0; j < 4; ++j)
            bfr[j] = *(const short8_t*)&sB[(wn + j * 16 + lr) * BKP + kg];
        #pragma unroll
        for (int i = 0; i < 4; ++i)
            #pragma unroll
            for (int j = 0; j < 4; ++j)
                acc[i][j] = __builtin_amdgcn_mfma_f32_16x16x32_bf16(af[i], bfr[j], acc[i][j], 0, 0, 0);
    }

    // epilogue: C/D layout col=lane&15, row=(lane>>4)*4 + reg   [verified m89/m91]
    const int cr = (lane >> 4) * 4;
    const int cc = lane & 15;
    #pragma unroll
    for (int i = 0; i < 4; ++i) {
        const int gm0 = bm + wm + i * 16 + cr;
        #pragma unroll
        for (int j = 0; j < 4; ++j) {
            const int gn = bn + wn + j * 16 + cc;
            if (gn < N) {
                float bval = 0.f;
                if (EPI == 1) bval = ldin(bias, (size_t)(bias_off + gn), f32f);
                #pragma unroll
                for (int r = 0; r < 4; ++r) {
                    float v = acc[i][j][r];
                    const size_t idx = (size_t)(gm0 + r) * ldc + gn;
                    if (EPI == 0) {
                        ((u16*)Cv)[idx] = f2b(v);
                    } else if (EPI == 1) {
                        v += bval;
                        v = (v > 20.f) ? v : log1pf(__expf(v));
                        ((u16*)Cv)[idx] = f2b(v);
                    } else {
                        ((float*)Cv)[idx] += v;
                    }
                }
            }
        }
    }
}

// ---- kernel: causal depthwise conv(K=4) + bias + silu ----
// reads x-half of xz [MPAD,3072] (internal bf16), writes xc [MPAD,1536]
__global__ void conv_silu(const u16* __restrict__ xz, const void* __restrict__ cw, int cwoff,
                          const void* __restrict__ cb, int cboff, u16* __restrict__ xc,
                          const int* __restrict__ flagp) {
    const int f32f = *flagp;
    const int gid = blockIdx.x * 256 + threadIdx.x;
    if (gid >= TOTAL * (DI / 8)) return;
    const int f = gid / (DI / 8);
    const int cg = gid % (DI / 8);
    const int c = cg * 8;
    int s = 0;
    while (f >= d_OFF[s + 1]) s++;
    const int t = f - d_OFF[s];

    float acc[8];
    #pragma unroll
    for (int i = 0; i < 8; ++i) acc[i] = ldin(cb, (size_t)cboff + c + i, f32f);
    float wv[32];
    #pragma unroll
    for (int i = 0; i < 32; ++i) wv[i] = ldin(cw, (size_t)cwoff + (size_t)c * 4 + i, f32f);

    #pragma unroll
    for (int j = 0; j < 4; ++j) {
        const int tj = t - 3 + j;
        if (tj >= 0) {
            U4 xv; xv.v = *(const uint4*)(xz + (size_t)(f - 3 + j) * (2 * DI) + c);
            #pragma unroll
            for (int i = 0; i < 8; ++i) acc[i] += b2f(xv.s[i]) * wv[i * 4 + j];
        }
    }
    U4 o;
    #pragma unroll
    for (int i = 0; i < 8; ++i) {
        const float a = acc[i];
        o.s[i] = f2b(a / (1.f + __expf(-a)));
    }
    *(uint4*)(xc + (size_t)f * DI + c) = o.v;
}

// ==================== chunk-parallel selective scan (3 passes) ====================
// chunk = 64 tokens; chunk ch covers global tokens [64*ch, 64*ch+64), never
// straddling a subject (all lengths/offsets divisible by 64).
// State buffers, layout [(ch*16 + n)*DI + c] (f32, coalesced over c):
//   Pb  = per-chunk decay product  prod_t exp(dt_t*A)      (aliases `normed`)
//   Sb  = per-chunk local exit state (h from 0)            (aliases `yb`)
//   Hin = per-chunk entry state (prefix over chunks)       (aliases Pb region)

// pass 1: local scan from 0 -> P, S.  grid (NCHUNK, 6) x 256
__global__ __launch_bounds__(256)
void scan_part1(const u16* __restrict__ xcb, const u16* __restrict__ dtb,
                const u16* __restrict__ dbl,
                const void* __restrict__ A_log, int aoff,
                const int* __restrict__ flagp,
                float* __restrict__ Pb, float* __restrict__ Sb) {
    __shared__ float sB[64 * 16];
    const int f32f = *flagp;
    const int ch = blockIdx.x;
    const int g0 = ch * 64;
    const int tid = threadIdx.x;
    // stage B (bf16 -> f32): 64 tokens x 16, threads 0..127 each unpack 8
    if (tid < 128) {
        const int t = tid >> 1, half = (tid & 1) * 8;
        uint4 q = *(const uint4*)(dbl + (size_t)(g0 + t) * DXP + DTR + half);
        float tmp[8]; unp8(q, tmp);
        *(float4*)&sB[t * 16 + half]     = *(float4*)&tmp[0];
        *(float4*)&sB[t * 16 + half + 4] = *(float4*)&tmp[4];
    }
    __syncthreads();
    const int lane = tid & 63, w = tid >> 6;
    const int c = (blockIdx.y * 4 + w) * 64 + lane;

    float A[16];
    #pragma unroll
    for (int n = 0; n < 16; ++n)
        A[n] = -__expf(ldin(A_log, (size_t)aoff + (size_t)c * DS + n, f32f));
    float h[16], P[16];
    #pragma unroll
    for (int n = 0; n < 16; ++n) { h[n] = 0.f; P[n] = 1.f; }

    u16 xu = xcb[(size_t)g0 * DI + c];
    u16 du = dtb[(size_t)g0 * DI + c];
    for (int t = 0; t < 64; ++t) {
        const float x = b2f(xu), dtv = b2f(du);
        if (t + 1 < 64) {
            xu = xcb[(size_t)(g0 + t + 1) * DI + c];
            du = dtb[(size_t)(g0 + t + 1) * DI + c];
        }
        float Bv[16];
        *(float4*)&Bv[0]  = *(float4*)&sB[t * 16 + 0];
        *(float4*)&Bv[4]  = *(float4*)&sB[t * 16 + 4];
        *(float4*)&Bv[8]  = *(float4*)&sB[t * 16 + 8];
        *(float4*)&Bv[12] = *(float4*)&sB[t * 16 + 12];
        const float dtx = dtv * x;
        #pragma unroll
        for (int n = 0; n < 16; ++n) {
            const float dA = __expf(dtv * A[n]);
            h[n] = dA * h[n] + dtx * Bv[n];
            P[n] *= dA;
        }
    }
    #pragma unroll
    for (int n = 0; n < 16; ++n) {
        const size_t idx = ((size_t)ch * 16 + n) * DI + c;
        Pb[idx] = P[n];
        Sb[idx] = h[n];
    }
}

// pass 2: sequential prefix over each subject's chunks -> Hin.
// Hin may ALIAS Pb (read P/S of a chunk before writing its Hin). No __restrict__.
__global__ __launch_bounds__(64)
void scan_part2(const float* Pb, const float* Sb, float* Hin) {
    const int bid = blockIdx.x;           // 0..191
    const int s = bid / 24, cg = bid % 24;
    const int c = cg * 64 + threadIdx.x;
    const int j0 = d_OFF[s] / 64;
    const int cnt = (d_OFF[s + 1] - d_OFF[s]) / 64;
    float h[16];
    #pragma unroll
    for (int n = 0; n < 16; ++n) h[n] = 0.f;
    for (int j = 0; j < cnt; ++j) {
        const int ch = j0 + j;
        float p[16], sv[16];
        #pragma unroll
        for (int n = 0; n < 16; ++n) {
            const size_t idx = ((size_t)ch * 16 + n) * DI + c;
            p[n] = Pb[idx]; sv[n] = Sb[idx];
        }
        #pragma unroll
        for (int n = 0; n < 16; ++n)
            Hin[((size_t)ch * 16 + n) * DI + c] = h[n];
        #pragma unroll
        for (int n = 0; n < 16; ++n)
            h[n] = p[n] * h[n] + sv[n];
    }
}

// pass 3: local scan seeded with Hin, emit gated y.  grid (NCHUNK, 6) x 256
__global__ __launch_bounds__(256)
void scan_part3(const u16* __restrict__ xcb, const u16* __restrict__ dtb,
                const u16* __restrict__ xz, const u16* __restrict__ dbl,
                const void* __restrict__ A_log, int aoff,
                const void* __restrict__ Dp, int doff,
                const float* __restrict__ Hin, u16* __restrict__ yb,
                const int* __restrict__ flagp) {
    __shared__ float sBC[64 * 32];
    const int f32f = *flagp;
    const int ch = blockIdx.x;
    const int g0 = ch * 64;
    const int tid = threadIdx.x;
    // stage B+C (bf16 -> f32): 64 tokens x 32, each thread unpacks 8
    {
        const int t = tid >> 2, r = (tid & 3) * 8;
        uint4 q = *(const uint4*)(dbl + (size_t)(g0 + t) * DXP + DTR + r);
        float tmp[8]; unp8(q, tmp);
        *(float4*)&sBC[t * 32 + r]     = *(float4*)&tmp[0];
        *(float4*)&sBC[t * 32 + r + 4] = *(float4*)&tmp[4];
    }
    __syncthreads();
    const int lane = tid & 63, w = tid >> 6;
    const int c = (blockIdx.y * 4 + w) * 64 + lane;

    float A[16];
    #pragma unroll
    for (int n = 0; n < 16; ++n)
        A[n] = -__expf(ldin(A_log, (size_t)aoff + (size_t)c * DS + n, f32f));
    const float Dv = ldin(Dp, (size_t)doff + c, f32f);
    float h[16];
    #pragma unroll
    for (int n = 0; n < 16; ++n) h[n] = Hin[((size_t)ch * 16 + n) * DI + c];

    u16 xu = xcb[(size_t)g0 * DI + c];
    u16 du = dtb[(size_t)g0 * DI + c];
    u16 zu = xz[(size_t)g0 * (2 * DI) + DI + c];
    for (int t = 0; t < 64; ++t) {
        const float x = b2f(xu), dtv = b2f(du), z = b2f(zu);
        if (t + 1 < 64) {
            xu = xcb[(size_t)(g0 + t + 1) * DI + c];
            du = dtb[(size_t)(g0 + t + 1) * DI + c];
            zu = xz[(size_t)(g0 + t + 1) * (2 * DI) + DI + c];
        }
        float Bv[16], Cvv[16];
        *(float4*)&Bv[0]   = *(float4*)&sBC[t * 32 + 0];
        *(float4*)&Bv[4]   = *(float4*)&sBC[t * 32 + 4];
        *(float4*)&Bv[8]   = *(float4*)&sBC[t * 32 + 8];
        *(float4*)&Bv[12]  = *(float4*)&sBC[t * 32 + 12];
        *(float4*)&Cvv[0]  = *(float4*)&sBC[t * 32 + 16];
        *(float4*)&Cvv[4]  = *(float4*)&sBC[t * 32 + 20];
        *(float4*)&Cvv[8]  = *(float4*)&sBC[t * 32 + 24];
        *(float4*)&Cvv[12] = *(float4*)&sBC[t * 32 + 28];
        const float dtx = dtv * x;
        float acc = 0.f;
        #pragma unroll
        for (int n = 0; n < 16; ++n) {
            const float dA = __expf(dtv * A[n]);
            h[n] = dA * h[n] + dtx * Bv[n];
            acc += h[n] * Cvv[n];
        }
        const float sig = 1.f / (1.f + __expf(-z));
        yb[(size_t)(g0 + t) * DI + c] = f2b((acc + x * Dv) * (z * sig));
    }
}

// ---- final: rmsnorm(h, norm_f_w) then rmsnorm(., out_norm_w) -> d_out ----
__global__ void final_norm(const float* __restrict__ h, const void* __restrict__ wf,
                           const void* __restrict__ wo, void* __restrict__ out,
                           const int* __restrict__ flagp) {
    const int f32f = *flagp;
    const int f = blockIdx.x;
    const int tid = threadIdx.x;
    float v[3]; float ss = 0.f;
    #pragma unroll
    for (int i = 0; i < 3; ++i) { v[i] = h[(size_t)f * DM + tid + 256 * i]; ss += v[i] * v[i]; }
    float tot = block_sum(ss);
    float rs = rsqrtf(tot * (1.f / DM) + EPSN);
    float ss2 = 0.f;
    #pragma unroll
    for (int i = 0; i < 3; ++i) {
        v[i] = v[i] * rs * ldin(wf, tid + 256 * i, f32f);
        ss2 += v[i] * v[i];
    }
    tot = block_sum(ss2);
    rs = rsqrtf(tot * (1.f / DM) + EPSN);
    #pragma unroll
    for (int i = 0; i < 3; ++i) {
        const float r = v[i] * rs * ldin(wo, tid + 256 * i, f32f);
        const size_t idx = (size_t)f * DM + tid + 256 * i;
        if (f32f) ((float*)out)[idx] = r;
        else      ((u16*)out)[idx] = f2b(r);
    }
}

extern "C" void kernel_launch(void* const* d_in, const int* in_sizes, int n_in,
                              void* d_out, int out_size, void* d_ws, size_t ws_size,
                              hipStream_t stream) {
    const int*  tokens     = (const int*)d_in[0];
    const void* embed      = d_in[1];
    const void* in_norm_w  = d_in[2];
    const void* out_norm_w = d_in[3];
    const void* norm_w     = d_in[4];
    const void* in_proj_w  = d_in[5];
    const void* conv_w     = d_in[6];
    const void* conv_b     = d_in[7];
    const void* x_proj_w   = d_in[8];
    const void* dt_proj_w  = d_in[9];
    const void* dt_proj_b  = d_in[10];
    const void* A_log      = d_in[11];
    const void* D_param    = d_in[12];
    const void* out_proj_w = d_in[13];
    const void* norm_f_w   = d_in[14];

    // workspace layout (byte offsets, all 16B aligned)
    char* ws = (char*)d_ws;
    float* h    = (float*)(ws);                     // MPAD*768*4  = 21,233,664
    u16* normed = (u16*)(ws + 21233664);            // MPAD*768*2  (scan: Pb/Hin alias)
    u16* xz     = (u16*)(ws + 31850496);            // MPAD*3072*2
    u16* xcb    = (u16*)(ws + 74317824);            // MPAD*1536*2
    u16* dbl    = (u16*)(ws + 95551488);            // MPAD*80*2
    u16* dtb    = (u16*)(ws + 96657408);            // MPAD*1536*2
    u16* yb     = (u16*)(ws + 117891072);           // MPAD*1536*2 (scan: Sb alias)
    u16* w_ip   = (u16*)(ws + 139124736);           // 2*3072*768  bf16
    u16* w_op   = (u16*)(ws + 148561920);           // 2*768*1536  bf16
    u16* w_xp   = (u16*)(ws + 153280512);           // 2*80*1536   bf16
    u16* w_dt   = (u16*)(ws + 153772032);           // 2*1536*48   bf16
    int* flag   = (int*)(ws + 154066944);
    // scan scratch aliases (NCHUNK*16*DI*4 = 10,518,528 B each):
    float* Pb  = (float*)normed;   // pass1 out / pass2 in; Hin overwrites in pass2
    float* Sb  = (float*)yb;       // pass1 out / pass2 in; dead before pass3 writes yb
    float* Hin = (float*)normed;

    detect_dtype<<<1, 64, 0, stream>>>((const u16*)embed, flag);

    cvt_f2b<<<(2 * 2 * DI * DM + 255) / 256, 256, 0, stream>>>((const float*)in_proj_w,  w_ip, 2 * 2 * DI * DM, flag);
    cvt_f2b<<<(2 * DM * DI + 255) / 256, 256, 0, stream>>>((const float*)out_proj_w, w_op, 2 * DM * DI, flag);
    cvt_f2b<<<(2 * DXP * DI + 255) / 256, 256, 0, stream>>>((const float*)x_proj_w,  w_xp, 2 * DXP * DI, flag);
    cvt_f2b<<<(2 * DI * DTR + 255) / 256, 256, 0, stream>>>((const float*)dt_proj_w, w_dt, 2 * DI * DTR, flag);

    embed_rms<<<TOTAL, 256, 0, stream>>>(tokens, embed, in_norm_w, h, flag);

    for (int l = 0; l < 2; ++l) {
        rms_f2b<<<TOTAL, 256, 0, stream>>>(h, norm_w, l * DM, normed, flag);
        // in_proj: [MPAD,768] x [3072,768]^T -> xz [MPAD,3072]
        gemm_bt<0><<<dim3(MPAD / TM, 3072 / TN), 256, 0, stream>>>(
            normed, (const u16*)in_proj_w + (size_t)l * 2 * DI * DM,
            w_ip + (size_t)l * 2 * DI * DM, xz, nullptr, 0, flag,
            MPAD, 2 * DI, DM, DM, DM, 2 * DI);
        conv_silu<<<(TOTAL * (DI / 8)) / 256, 256, 0, stream>>>(
            xz, conv_w, l * DI * 4, conv_b, l * DI, xcb, flag);
        // x_proj: [MPAD,1536] x [80,1536]^T -> dbl [MPAD,80]
        gemm_bt<0><<<dim3(MPAD / TM, 1), 256, 0, stream>>>(
            xcb, (const u16*)x_proj_w + (size_t)l * DXP * DI,
            w_xp + (size_t)l * DXP * DI, dbl, nullptr, 0, flag,
            MPAD, DXP, DI, DI, DI, DXP);
        // dt_proj: [MPAD,48](lda=80) x [1536,48]^T -> softplus(+b) -> dtb [MPAD,1536]
        gemm_bt<1><<<dim3(MPAD / TM, DI / TN), 256, 0, stream>>>(
            dbl, (const u16*)dt_proj_w + (size_t)l * DI * DTR,
            w_dt + (size_t)l * DI * DTR, dtb, dt_proj_b, l * DI, flag,
            MPAD, DI, DTR, DXP, DTR, DI);
        // chunk-parallel selective scan
        scan_part1<<<dim3(NCHUNK, 6), 256, 0, stream>>>(
            xcb, dtb, dbl, A_log, l * DI * DS, flag, Pb, Sb);
        scan_part2<<<NSUBJ * 24, 64, 0, stream>>>(Pb, Sb, Hin);
        scan_part3<<<dim3(NCHUNK, 6), 256, 0, stream>>>(
            xcb, dtb, xz, dbl, A_log, l * DI * DS, D_param, l * DI, Hin, yb, flag);
        // out_proj: [MPAD,1536] x [768,1536]^T -> h += (residual)
        gemm_bt<2><<<dim3(MPAD / TM, DM / TN), 256, 0, stream>>>(
            yb, (const u16*)out_proj_w + (size_t)l * DM * DI,
            w_op + (size_t)l * DM * DI, h, nullptr, 0, flag,
            MPAD, DM, DI, DI, DI, DM);
    }

    final_norm<<<TOTAL, 256, 0, stream>>>(h, norm_f_w, out_norm_w, d_out, flag);
}

// Round 4
// 970.910 us; speedup vs baseline: 2.2756x; 1.1496x over previous
//
#include <hip/hip_runtime.h>
#include <hip/hip_bf16.h>

typedef unsigned short u16;
typedef unsigned int u32;
typedef __attribute__((ext_vector_type(8))) short short8_t;   // 8 bf16 (4 VGPRs)
typedef __attribute__((ext_vector_type(4))) float f32x4;

// ---- static problem config ----
#define NSUBJ 8
#define TOTAL 6848
#define MPAD  6912          // 54 * 128
#define DM    768
#define DI    1536
#define DS    16
#define DTR   48
#define DXP   80            // DTR + 2*DS
#define EPSN  1e-5f
#define NCHUNK 107          // TOTAL / 64; every subject length & offset divisible by 64

__constant__ int d_OFF[NSUBJ + 1] = {0, 1024, 1920, 2688, 3712, 4224, 4864, 5824, 6848};

// ---- helpers ----
__device__ __forceinline__ float b2f(u16 u) {
    return __uint_as_float(((u32)u) << 16);
}
__device__ __forceinline__ u16 f2b(float f) {
    u32 u = __float_as_uint(f);
    u32 r = (u + 0x7FFFu + ((u >> 16) & 1u)) >> 16;
    return (u16)r;
}
// dual-path input load: inputs may be f32 (flag=1) or bf16 (flag=0)
__device__ __forceinline__ float ldin(const void* p, size_t i, int f32f) {
    return f32f ? ((const float*)p)[i] : b2f(((const u16*)p)[i]);
}
union U4 { uint4 v; u16 s[8]; };

__device__ __forceinline__ void unp8(uint4 v, float* o) {
    u32 a0 = v.x, a1 = v.y, a2 = v.z, a3 = v.w;
    o[0] = __uint_as_float(a0 << 16);  o[1] = __uint_as_float(a0 & 0xFFFF0000u);
    o[2] = __uint_as_float(a1 << 16);  o[3] = __uint_as_float(a1 & 0xFFFF0000u);
    o[4] = __uint_as_float(a2 << 16);  o[5] = __uint_as_float(a2 & 0xFFFF0000u);
    o[6] = __uint_as_float(a3 << 16);  o[7] = __uint_as_float(a3 & 0xFFFF0000u);
}

// block of 256 threads (4 waves) sums v across the block
__device__ __forceinline__ float block_sum(float v) {
    __shared__ float sbuf[8];
    __syncthreads();
    #pragma unroll
    for (int o = 32; o > 0; o >>= 1) v += __shfl_down(v, o, 64);
    const int lane = threadIdx.x & 63, w = threadIdx.x >> 6;
    if (lane == 0) sbuf[w] = v;
    __syncthreads();
    if (threadIdx.x == 0) sbuf[4] = sbuf[0] + sbuf[1] + sbuf[2] + sbuf[3];
    __syncthreads();
    return sbuf[4];
}

// ---- dtype detection: f32 data read as u16 has ~44% "huge-exponent" low halves ----
__global__ void detect_dtype(const u16* __restrict__ probe, int* __restrict__ flag) {
    const int lane = threadIdx.x;
    int cnt = 0;
    for (int i = 0; i < 32; ++i) {
        const u16 v = probe[lane * 32 + i];
        if (((v >> 7) & 0xFF) >= 0x90) cnt++;
    }
    #pragma unroll
    for (int o = 32; o > 0; o >>= 1) cnt += __shfl_down(cnt, o, 64);
    if (lane == 0) *flag = (cnt > 64) ? 1 : 0;
}

// ---- f32 -> bf16 weight conversion (no-op when inputs already bf16) ----
__global__ void cvt_f2b(const float* __restrict__ src, u16* __restrict__ dst, int n,
                        const int* __restrict__ flagp) {
    if (*flagp == 0) return;
    const int i = blockIdx.x * 256 + threadIdx.x;
    if (i < n) dst[i] = f2b(src[i]);
}

// ---- precompute: conv weights [l][tap][c] f32, conv bias f32, nA = -exp(A_log) [l][n][c] ----
__global__ void prep_conv(const void* __restrict__ cw, const void* __restrict__ cb,
                          const void* __restrict__ A_log,
                          float* __restrict__ cwT, float* __restrict__ cbF,
                          float* __restrict__ nA, const int* __restrict__ flagp) {
    const int f32f = *flagp;
    const int i = blockIdx.x * 256 + threadIdx.x;
    if (i < 2 * 4 * DI) {       // cwT[l][tap][c] = cw[l][c][tap]
        const int l = i / (4 * DI), r = i - l * 4 * DI;
        const int tap = r / DI, c = r - tap * DI;
        cwT[i] = ldin(cw, (size_t)l * DI * 4 + (size_t)c * 4 + tap, f32f);
    }
    if (i < 2 * DI) cbF[i] = ldin(cb, i, f32f);
    if (i < 2 * 16 * DI) {      // nA[l][n][c] = -exp(A_log[l][c][n])
        const int l = i / (16 * DI), r = i - l * 16 * DI;
        const int n = r / DI, c = r - n * DI;
        nA[i] = -__expf(ldin(A_log, (size_t)l * DI * DS + (size_t)c * DS + n, f32f));
    }
}

// ---- kernel 1: embedding gather + rmsnorm(in_norm_w) -> h (f32, compact layout) ----
__global__ void embed_rms(const int* __restrict__ tokens, const void* __restrict__ embed,
                          const void* __restrict__ w, float* __restrict__ h,
                          const int* __restrict__ flagp) {
    const int f32f = *flagp;
    const int f = blockIdx.x;
    const int tid = threadIdx.x;
    const int row = tokens[f];
    float v[3]; float ss = 0.f;
    #pragma unroll
    for (int i = 0; i < 3; ++i) {
        v[i] = ldin(embed, (size_t)row * DM + tid + 256 * i, f32f);
        ss += v[i] * v[i];
    }
    const float tot = block_sum(ss);
    const float rs = rsqrtf(tot * (1.f / DM) + EPSN);
    #pragma unroll
    for (int i = 0; i < 3; ++i)
        h[(size_t)f * DM + tid + 256 * i] = v[i] * rs * ldin(w, tid + 256 * i, f32f);
}

// ---- kernel 2: rmsnorm(h f32, w) -> normed bf16 ----
__global__ void rms_f2b(const float* __restrict__ h, const void* __restrict__ w, int woff,
                        u16* __restrict__ out, const int* __restrict__ flagp) {
    const int f32f = *flagp;
    const int f = blockIdx.x;
    const int tid = threadIdx.x;
    float v[3]; float ss = 0.f;
    #pragma unroll
    for (int i = 0; i < 3; ++i) { v[i] = h[(size_t)f * DM + tid + 256 * i]; ss += v[i] * v[i]; }
    const float tot = block_sum(ss);
    const float rs = rsqrtf(tot * (1.f / DM) + EPSN);
    #pragma unroll
    for (int i = 0; i < 3; ++i)
        out[(size_t)f * DM + tid + 256 * i] =
            f2b(v[i] * rs * ldin(w, woff + tid + 256 * i, f32f));
}

// ---- MFMA GEMM: C[M,N] (+epi) = A[M,K](lda) * B[N,K](ldb)^T, bf16 in, f32 acc ----
// EPI: 0 = store bf16; 1 = softplus(acc + bias[n]) store bf16; 2 = C(f32) += acc
#define TM 128
#define TN 128
#define BK 32
#define BKP 40   // padded LDS leading dim (bf16 elems): 80B rows -> conflict-free b128 reads

template <int EPI>
__global__ void gemm_bt(const u16* __restrict__ A, const u16* __restrict__ Borig,
                        const u16* __restrict__ Bcv, void* __restrict__ Cv,
                        const void* __restrict__ bias, int bias_off,
                        const int* __restrict__ flagp,
                        int M, int N, int K, int lda, int ldb, int ldc) {
    __shared__ u16 sA[TM * BKP];
    __shared__ u16 sB[TN * BKP];
    const int f32f = *flagp;
    const u16* __restrict__ B = f32f ? Bcv : Borig;
    const int tid = threadIdx.x;
    const int bm = blockIdx.x * TM;
    const int bn = blockIdx.y * TN;
    const int lane = tid & 63, w = tid >> 6;
    const int wm = (w >> 1) * 64, wn = (w & 1) * 64;
    const int lr = lane & 15;
    const int kg = (lane >> 4) * 8;

    f32x4 acc[4][4];
    #pragma unroll
    for (int i = 0; i < 4; ++i)
        #pragma unroll
        for (int j = 0; j < 4; ++j)
            acc[i][j] = (f32x4){0.f, 0.f, 0.f, 0.f};

    const int sr = tid >> 1;            // staging row 0..127 (2 threads/row)
    const int skc = (tid & 1) * 16;     // staging k-offset 0 or 16

    for (int k0 = 0; k0 < K; k0 += BK) {
        __syncthreads();
        // stage A tile (M rows always valid: M is a multiple of 128)
        {
            uint4 v0 = {0,0,0,0}, v1 = {0,0,0,0};
            const size_t go = (size_t)(bm + sr) * lda + (k0 + skc);
            if (k0 + skc < K)     v0 = *(const uint4*)(A + go);
            if (k0 + skc + 8 < K) v1 = *(const uint4*)(A + go + 8);
            *(uint4*)&sA[sr * BKP + skc]     = v0;
            *(uint4*)&sA[sr * BKP + skc + 8] = v1;
        }
        // stage B tile (guard n < N and k < K)
        {
            uint4 v0 = {0,0,0,0}, v1 = {0,0,0,0};
            const int gn = bn + sr;
            if (gn < N) {
                const size_t go = (size_t)gn * ldb + (k0 + skc);
                if (k0 + skc < K)     v0 = *(const uint4*)(B + go);
                if (k0 + skc + 8 < K) v1 = *(const uint4*)(B + go + 8);
            }
            *(uint4*)&sB[sr * BKP + skc]     = v0;
            *(uint4*)&sB[sr * BKP + skc + 8] = v1;
        }
        __syncthreads();

        short8_t af[4], bfr[4];
        #pragma unroll
        for (int i = 0; i < 4; ++i)
            af[i] = *(const short8_t*)&sA[(wm + i * 16 + lr) * BKP + kg];
        #pragma unroll
        for (int j = 0; j < 4; ++j)
            bfr[j] = *(const short8_t*)&sB[(wn + j * 16 + lr) * BKP + kg];
        #pragma unroll
        for (int i = 0; i < 4; ++i)
            #pragma unroll
            for (int j = 0; j < 4; ++j)
                acc[i][j] = __builtin_amdgcn_mfma_f32_16x16x32_bf16(af[i], bfr[j], acc[i][j], 0, 0, 0);
    }

    // epilogue: C/D layout col=lane&15, row=(lane>>4)*4 + reg   [verified m89/m91]
    const int cr = (lane >> 4) * 4;
    const int cc = lane & 15;
    #pragma unroll
    for (int i = 0; i < 4; ++i) {
        const int gm0 = bm + wm + i * 16 + cr;
        #pragma unroll
        for (int j = 0; j < 4; ++j) {
            const int gn = bn + wn + j * 16 + cc;
            if (gn < N) {
                float bval = 0.f;
                if (EPI == 1) bval = ldin(bias, (size_t)(bias_off + gn), f32f);
                #pragma unroll
                for (int r = 0; r < 4; ++r) {
                    float v = acc[i][j][r];
                    const size_t idx = (size_t)(gm0 + r) * ldc + gn;
                    if (EPI == 0) {
                        ((u16*)Cv)[idx] = f2b(v);
                    } else if (EPI == 1) {
                        v += bval;
                        v = (v > 20.f) ? v : log1pf(__expf(v));
                        ((u16*)Cv)[idx] = f2b(v);
                    } else {
                        ((float*)Cv)[idx] += v;
                    }
                }
            }
        }
    }
}

// ---- causal depthwise conv(K=4) + bias + silu; fully coalesced ----
// thread owns 2 consecutive channels of one token; weights pre-transposed [tap][c] f32
__global__ void conv_silu(const u16* __restrict__ xz, const float* __restrict__ cwT,
                          const float* __restrict__ cbF, u16* __restrict__ xc) {
    const int gid = blockIdx.x * 256 + threadIdx.x;
    if (gid >= TOTAL * (DI / 2)) return;
    const int f = gid / (DI / 2);
    const int c = (gid - f * (DI / 2)) * 2;
    int s = 0;
    while (f >= d_OFF[s + 1]) s++;
    const int t = f - d_OFF[s];

    float2 acc = *(const float2*)(cbF + c);
    #pragma unroll
    for (int j = 0; j < 4; ++j) {
        if (t - 3 + j >= 0) {
            const u32 xp = *(const u32*)(xz + (size_t)(f - 3 + j) * (2 * DI) + c);
            const float2 wv = *(const float2*)(cwT + j * DI + c);
            acc.x += __uint_as_float(xp << 16) * wv.x;
            acc.y += __uint_as_float(xp & 0xFFFF0000u) * wv.y;
        }
    }
    const float s0 = acc.x / (1.f + __expf(-acc.x));
    const float s1 = acc.y / (1.f + __expf(-acc.y));
    *(u32*)(xc + (size_t)f * DI + c) = (u32)f2b(s0) | ((u32)f2b(s1) << 16);
}

// ==================== chunk-parallel selective scan (3 passes) ====================
// chunk = 64 tokens; never straddles a subject. State layout [(ch*16+n)*DI + c] f32.
//   Pb (aliases `normed`), Sb (aliases `yb`), Hin (aliases Pb region)

// pass 1: local scan from 0 -> P, S.  grid (NCHUNK, 6) x 256
__global__ __launch_bounds__(256)
void scan_part1(const u16* __restrict__ xcb, const u16* __restrict__ dtb,
                const u16* __restrict__ dbl,
                const float* __restrict__ nA, int aoff,
                float* __restrict__ Pb, float* __restrict__ Sb) {
    __shared__ float sB[64 * 16];
    const int ch = blockIdx.x;
    const int g0 = ch * 64;
    const int tid = threadIdx.x;
    if (tid < 128) {
        const int t = tid >> 1, half = (tid & 1) * 8;
        uint4 q = *(const uint4*)(dbl + (size_t)(g0 + t) * DXP + DTR + half);
        float tmp[8]; unp8(q, tmp);
        *(float4*)&sB[t * 16 + half]     = *(float4*)&tmp[0];
        *(float4*)&sB[t * 16 + half + 4] = *(float4*)&tmp[4];
    }
    __syncthreads();
    const int lane = tid & 63, w = tid >> 6;
    const int c = (blockIdx.y * 4 + w) * 64 + lane;

    float A[16];
    #pragma unroll
    for (int n = 0; n < 16; ++n) A[n] = nA[aoff + n * DI + c];
    float h[16], P[16];
    #pragma unroll
    for (int n = 0; n < 16; ++n) { h[n] = 0.f; P[n] = 1.f; }

    u16 xu = xcb[(size_t)g0 * DI + c];
    u16 du = dtb[(size_t)g0 * DI + c];
    for (int t = 0; t < 64; ++t) {
        const float x = b2f(xu), dtv = b2f(du);
        if (t + 1 < 64) {
            xu = xcb[(size_t)(g0 + t + 1) * DI + c];
            du = dtb[(size_t)(g0 + t + 1) * DI + c];
        }
        float Bv[16];
        *(float4*)&Bv[0]  = *(float4*)&sB[t * 16 + 0];
        *(float4*)&Bv[4]  = *(float4*)&sB[t * 16 + 4];
        *(float4*)&Bv[8]  = *(float4*)&sB[t * 16 + 8];
        *(float4*)&Bv[12] = *(float4*)&sB[t * 16 + 12];
        const float dtx = dtv * x;
        #pragma unroll
        for (int n = 0; n < 16; ++n) {
            const float dA = __expf(dtv * A[n]);
            h[n] = dA * h[n] + dtx * Bv[n];
            P[n] *= dA;
        }
    }
    #pragma unroll
    for (int n = 0; n < 16; ++n) {
        const size_t idx = ((size_t)ch * 16 + n) * DI + c;
        Pb[idx] = P[n];
        Sb[idx] = h[n];
    }
}

// pass 2: sequential prefix over each subject's chunks -> Hin (may alias Pb)
__global__ __launch_bounds__(64)
void scan_part2(const float* Pb, const float* Sb, float* Hin) {
    const int bid = blockIdx.x;           // 0..191
    const int s = bid / 24, cg = bid % 24;
    const int c = cg * 64 + threadIdx.x;
    const int j0 = d_OFF[s] / 64;
    const int cnt = (d_OFF[s + 1] - d_OFF[s]) / 64;
    float h[16];
    #pragma unroll
    for (int n = 0; n < 16; ++n) h[n] = 0.f;
    for (int j = 0; j < cnt; ++j) {
        const int ch = j0 + j;
        float p[16], sv[16];
        #pragma unroll
        for (int n = 0; n < 16; ++n) {
            const size_t idx = ((size_t)ch * 16 + n) * DI + c;
            p[n] = Pb[idx]; sv[n] = Sb[idx];
        }
        #pragma unroll
        for (int n = 0; n < 16; ++n)
            Hin[((size_t)ch * 16 + n) * DI + c] = h[n];
        #pragma unroll
        for (int n = 0; n < 16; ++n)
            h[n] = p[n] * h[n] + sv[n];
    }
}

// pass 3: local scan seeded with Hin, emit gated y.  grid (NCHUNK, 6) x 256
__global__ __launch_bounds__(256)
void scan_part3(const u16* __restrict__ xcb, const u16* __restrict__ dtb,
                const u16* __restrict__ xz, const u16* __restrict__ dbl,
                const float* __restrict__ nA, int aoff,
                const void* __restrict__ Dp, int doff,
                const float* __restrict__ Hin, u16* __restrict__ yb,
                const int* __restrict__ flagp) {
    __shared__ float sBC[64 * 32];
    const int f32f = *flagp;
    const int ch = blockIdx.x;
    const int g0 = ch * 64;
    const int tid = threadIdx.x;
    {
        const int t = tid >> 2, r = (tid & 3) * 8;
        uint4 q = *(const uint4*)(dbl + (size_t)(g0 + t) * DXP + DTR + r);
        float tmp[8]; unp8(q, tmp);
        *(float4*)&sBC[t * 32 + r]     = *(float4*)&tmp[0];
        *(float4*)&sBC[t * 32 + r + 4] = *(float4*)&tmp[4];
    }
    __syncthreads();
    const int lane = tid & 63, w = tid >> 6;
    const int c = (blockIdx.y * 4 + w) * 64 + lane;

    float A[16];
    #pragma unroll
    for (int n = 0; n < 16; ++n) A[n] = nA[aoff + n * DI + c];
    const float Dv = ldin(Dp, (size_t)doff + c, f32f);
    float h[16];
    #pragma unroll
    for (int n = 0; n < 16; ++n) h[n] = Hin[((size_t)ch * 16 + n) * DI + c];

    u16 xu = xcb[(size_t)g0 * DI + c];
    u16 du = dtb[(size_t)g0 * DI + c];
    u16 zu = xz[(size_t)g0 * (2 * DI) + DI + c];
    for (int t = 0; t < 64; ++t) {
        const float x = b2f(xu), dtv = b2f(du), z = b2f(zu);
        if (t + 1 < 64) {
            xu = xcb[(size_t)(g0 + t + 1) * DI + c];
            du = dtb[(size_t)(g0 + t + 1) * DI + c];
            zu = xz[(size_t)(g0 + t + 1) * (2 * DI) + DI + c];
        }
        float Bv[16], Cvv[16];
        *(float4*)&Bv[0]   = *(float4*)&sBC[t * 32 + 0];
        *(float4*)&Bv[4]   = *(float4*)&sBC[t * 32 + 4];
        *(float4*)&Bv[8]   = *(float4*)&sBC[t * 32 + 8];
        *(float4*)&Bv[12]  = *(float4*)&sBC[t * 32 + 12];
        *(float4*)&Cvv[0]  = *(float4*)&sBC[t * 32 + 16];
        *(float4*)&Cvv[4]  = *(float4*)&sBC[t * 32 + 20];
        *(float4*)&Cvv[8]  = *(float4*)&sBC[t * 32 + 24];
        *(float4*)&Cvv[12] = *(float4*)&sBC[t * 32 + 28];
        const float dtx = dtv * x;
        float acc = 0.f;
        #pragma unroll
        for (int n = 0; n < 16; ++n) {
            const float dA = __expf(dtv * A[n]);
            h[n] = dA * h[n] + dtx * Bv[n];
            acc += h[n] * Cvv[n];
        }
        const float sig = 1.f / (1.f + __expf(-z));
        yb[(size_t)(g0 + t) * DI + c] = f2b((acc + x * Dv) * (z * sig));
    }
}

// ---- final: rmsnorm(h, norm_f_w) then rmsnorm(., out_norm_w) -> d_out ----
__global__ void final_norm(const float* __restrict__ h, const void* __restrict__ wf,
                           const void* __restrict__ wo, void* __restrict__ out,
                           const int* __restrict__ flagp) {
    const int f32f = *flagp;
    const int f = blockIdx.x;
    const int tid = threadIdx.x;
    float v[3]; float ss = 0.f;
    #pragma unroll
    for (int i = 0; i < 3; ++i) { v[i] = h[(size_t)f * DM + tid + 256 * i]; ss += v[i] * v[i]; }
    float tot = block_sum(ss);
    float rs = rsqrtf(tot * (1.f / DM) + EPSN);
    float ss2 = 0.f;
    #pragma unroll
    for (int i = 0; i < 3; ++i) {
        v[i] = v[i] * rs * ldin(wf, tid + 256 * i, f32f);
        ss2 += v[i] * v[i];
    }
    tot = block_sum(ss2);
    rs = rsqrtf(tot * (1.f / DM) + EPSN);
    #pragma unroll
    for (int i = 0; i < 3; ++i) {
        const float r = v[i] * rs * ldin(wo, tid + 256 * i, f32f);
        const size_t idx = (size_t)f * DM + tid + 256 * i;
        if (f32f) ((float*)out)[idx] = r;
        else      ((u16*)out)[idx] = f2b(r);
    }
}

extern "C" void kernel_launch(void* const* d_in, const int* in_sizes, int n_in,
                              void* d_out, int out_size, void* d_ws, size_t ws_size,
                              hipStream_t stream) {
    const int*  tokens     = (const int*)d_in[0];
    const void* embed      = d_in[1];
    const void* in_norm_w  = d_in[2];
    const void* out_norm_w = d_in[3];
    const void* norm_w     = d_in[4];
    const void* in_proj_w  = d_in[5];
    const void* conv_w     = d_in[6];
    const void* conv_b     = d_in[7];
    const void* x_proj_w   = d_in[8];
    const void* dt_proj_w  = d_in[9];
    const void* dt_proj_b  = d_in[10];
    const void* A_log      = d_in[11];
    const void* D_param    = d_in[12];
    const void* out_proj_w = d_in[13];
    const void* norm_f_w   = d_in[14];

    // workspace layout (byte offsets, all 16B aligned)
    char* ws = (char*)d_ws;
    float* h    = (float*)(ws);                     // MPAD*768*4  = 21,233,664
    u16* normed = (u16*)(ws + 21233664);            // MPAD*768*2  (scan: Pb/Hin alias)
    u16* xz     = (u16*)(ws + 31850496);            // MPAD*3072*2
    u16* xcb    = (u16*)(ws + 74317824);            // MPAD*1536*2
    u16* dbl    = (u16*)(ws + 95551488);            // MPAD*80*2
    u16* dtb    = (u16*)(ws + 96657408);            // MPAD*1536*2
    u16* yb     = (u16*)(ws + 117891072);           // MPAD*1536*2 (scan: Sb alias)
    u16* w_ip   = (u16*)(ws + 139124736);           // 2*3072*768  bf16
    u16* w_op   = (u16*)(ws + 148561920);           // 2*768*1536  bf16
    u16* w_xp   = (u16*)(ws + 153280512);           // 2*80*1536   bf16
    u16* w_dt   = (u16*)(ws + 153772032);           // 2*1536*48   bf16
    int* flag   = (int*)(ws + 154066944);
    float* cwT  = (float*)(ws + 154067200);         // 2*4*1536 f32  = 49,152 B
    float* cbF  = (float*)(ws + 154116352);         // 2*1536 f32    = 12,288 B
    float* nA   = (float*)(ws + 154128640);         // 2*16*1536 f32 = 196,608 B
    // total ~154.33 MB
    float* Pb  = (float*)normed;   // pass1 out / pass2 in; Hin overwrites in pass2
    float* Sb  = (float*)yb;       // pass1 out / pass2 in; dead before pass3 writes yb
    float* Hin = (float*)normed;

    detect_dtype<<<1, 64, 0, stream>>>((const u16*)embed, flag);

    cvt_f2b<<<(2 * 2 * DI * DM + 255) / 256, 256, 0, stream>>>((const float*)in_proj_w,  w_ip, 2 * 2 * DI * DM, flag);
    cvt_f2b<<<(2 * DM * DI + 255) / 256, 256, 0, stream>>>((const float*)out_proj_w, w_op, 2 * DM * DI, flag);
    cvt_f2b<<<(2 * DXP * DI + 255) / 256, 256, 0, stream>>>((const float*)x_proj_w,  w_xp, 2 * DXP * DI, flag);
    cvt_f2b<<<(2 * DI * DTR + 255) / 256, 256, 0, stream>>>((const float*)dt_proj_w, w_dt, 2 * DI * DTR, flag);
    prep_conv<<<(2 * 16 * DI + 255) / 256, 256, 0, stream>>>(conv_w, conv_b, A_log, cwT, cbF, nA, flag);

    embed_rms<<<TOTAL, 256, 0, stream>>>(tokens, embed, in_norm_w, h, flag);

    for (int l = 0; l < 2; ++l) {
        rms_f2b<<<TOTAL, 256, 0, stream>>>(h, norm_w, l * DM, normed, flag);
        // in_proj: [MPAD,768] x [3072,768]^T -> xz [MPAD,3072]
        gemm_bt<0><<<dim3(MPAD / TM, 3072 / TN), 256, 0, stream>>>(
            normed, (const u16*)in_proj_w + (size_t)l * 2 * DI * DM,
            w_ip + (size_t)l * 2 * DI * DM, xz, nullptr, 0, flag,
            MPAD, 2 * DI, DM, DM, DM, 2 * DI);
        conv_silu<<<(TOTAL * (DI / 2) + 255) / 256, 256, 0, stream>>>(
            xz, cwT + (size_t)l * 4 * DI, cbF + (size_t)l * DI, xcb);
        // x_proj: [MPAD,1536] x [80,1536]^T -> dbl [MPAD,80]
        gemm_bt<0><<<dim3(MPAD / TM, 1), 256, 0, stream>>>(
            xcb, (const u16*)x_proj_w + (size_t)l * DXP * DI,
            w_xp + (size_t)l * DXP * DI, dbl, nullptr, 0, flag,
            MPAD, DXP, DI, DI, DI, DXP);
        // dt_proj: [MPAD,48](lda=80) x [1536,48]^T -> softplus(+b) -> dtb [MPAD,1536]
        gemm_bt<1><<<dim3(MPAD / TM, DI / TN), 256, 0, stream>>>(
            dbl, (const u16*)dt_proj_w + (size_t)l * DI * DTR,
            w_dt + (size_t)l * DI * DTR, dtb, dt_proj_b, l * DI, flag,
            MPAD, DI, DTR, DXP, DTR, DI);
        // chunk-parallel selective scan
        scan_part1<<<dim3(NCHUNK, 6), 256, 0, stream>>>(
            xcb, dtb, dbl, nA, l * 16 * DI, Pb, Sb);
        scan_part2<<<NSUBJ * 24, 64, 0, stream>>>(Pb, Sb, Hin);
        scan_part3<<<dim3(NCHUNK, 6), 256, 0, stream>>>(
            xcb, dtb, xz, dbl, nA, l * 16 * DI, D_param, l * DI, Hin, yb, flag);
        // out_proj: [MPAD,1536] x [768,1536]^T -> h += (residual)
        gemm_bt<2><<<dim3(MPAD / TM, DM / TN), 256, 0, stream>>>(
            yb, (const u16*)out_proj_w + (size_t)l * DM * DI,
            w_op + (size_t)l * DM * DI, h, nullptr, 0, flag,
            MPAD, DM, DI, DI, DI, DM);
    }

    final_norm<<<TOTAL, 256, 0, stream>>>(h, norm_f_w, out_norm_w, d_out, flag);
}

// Round 5
// 892.980 us; speedup vs baseline: 2.4742x; 1.0873x over previous
//
#include <hip/hip_runtime.h>
#include <hip/hip_bf16.h>

typedef unsigned short u16;
typedef unsigned int u32;
typedef __attribute__((ext_vector_type(8))) short short8_t;   // 8 bf16 (4 VGPRs)
typedef __attribute__((ext_vector_type(4))) float f32x4;

// ---- static problem config ----
#define NSUBJ 8
#define TOTAL 6848
#define MPAD  6912          // 54 * 128
#define DM    768
#define DI    1536
#define DS    16
#define DTR   48
#define DXP   80            // DTR + 2*DS
#define EPSN  1e-5f
#define NCHUNK 107          // TOTAL / 64; every subject length & offset divisible by 64

__constant__ int d_OFF[NSUBJ + 1] = {0, 1024, 1920, 2688, 3712, 4224, 4864, 5824, 6848};

// ---- helpers ----
__device__ __forceinline__ float b2f(u16 u) {
    return __uint_as_float(((u32)u) << 16);
}
__device__ __forceinline__ u16 f2b(float f) {
    u32 u = __float_as_uint(f);
    u32 r = (u + 0x7FFFu + ((u >> 16) & 1u)) >> 16;
    return (u16)r;
}
__device__ __forceinline__ float ldin(const void* p, size_t i, int f32f) {
    return f32f ? ((const float*)p)[i] : b2f(((const u16*)p)[i]);
}
union U4 { uint4 v; u16 s[8]; };

__device__ __forceinline__ void unp8(uint4 v, float* o) {
    u32 a0 = v.x, a1 = v.y, a2 = v.z, a3 = v.w;
    o[0] = __uint_as_float(a0 << 16);  o[1] = __uint_as_float(a0 & 0xFFFF0000u);
    o[2] = __uint_as_float(a1 << 16);  o[3] = __uint_as_float(a1 & 0xFFFF0000u);
    o[4] = __uint_as_float(a2 << 16);  o[5] = __uint_as_float(a2 & 0xFFFF0000u);
    o[6] = __uint_as_float(a3 << 16);  o[7] = __uint_as_float(a3 & 0xFFFF0000u);
}

__device__ __forceinline__ float block_sum(float v) {
    __shared__ float sbuf[8];
    __syncthreads();
    #pragma unroll
    for (int o = 32; o > 0; o >>= 1) v += __shfl_down(v, o, 64);
    const int lane = threadIdx.x & 63, w = threadIdx.x >> 6;
    if (lane == 0) sbuf[w] = v;
    __syncthreads();
    if (threadIdx.x == 0) sbuf[4] = sbuf[0] + sbuf[1] + sbuf[2] + sbuf[3];
    __syncthreads();
    return sbuf[4];
}

// ---- dtype detection ----
__global__ void detect_dtype(const u16* __restrict__ probe, int* __restrict__ flag) {
    const int lane = threadIdx.x;
    int cnt = 0;
    for (int i = 0; i < 32; ++i) {
        const u16 v = probe[lane * 32 + i];
        if (((v >> 7) & 0xFF) >= 0x90) cnt++;
    }
    #pragma unroll
    for (int o = 32; o > 0; o >>= 1) cnt += __shfl_down(cnt, o, 64);
    if (lane == 0) *flag = (cnt > 64) ? 1 : 0;
}

__global__ void cvt_f2b(const float* __restrict__ src, u16* __restrict__ dst, int n,
                        const int* __restrict__ flagp) {
    if (*flagp == 0) return;
    const int i = blockIdx.x * 256 + threadIdx.x;
    if (i < n) dst[i] = f2b(src[i]);
}

// ---- precompute: conv weights [l][tap][c] f32, conv bias f32, nA = -exp(A_log) [l][n][c] ----
__global__ void prep_conv(const void* __restrict__ cw, const void* __restrict__ cb,
                          const void* __restrict__ A_log,
                          float* __restrict__ cwT, float* __restrict__ cbF,
                          float* __restrict__ nA, const int* __restrict__ flagp) {
    const int f32f = *flagp;
    const int i = blockIdx.x * 256 + threadIdx.x;
    if (i < 2 * 4 * DI) {
        const int l = i / (4 * DI), r = i - l * 4 * DI;
        const int tap = r / DI, c = r - tap * DI;
        cwT[i] = ldin(cw, (size_t)l * DI * 4 + (size_t)c * 4 + tap, f32f);
    }
    if (i < 2 * DI) cbF[i] = ldin(cb, i, f32f);
    if (i < 2 * 16 * DI) {
        const int l = i / (16 * DI), r = i - l * 16 * DI;
        const int n = r / DI, c = r - n * DI;
        nA[i] = -__expf(ldin(A_log, (size_t)l * DI * DS + (size_t)c * DS + n, f32f));
    }
}

// ---- embedding gather + rmsnorm -> h f32 ----
__global__ void embed_rms(const int* __restrict__ tokens, const void* __restrict__ embed,
                          const void* __restrict__ w, float* __restrict__ h,
                          const int* __restrict__ flagp) {
    const int f32f = *flagp;
    const int f = blockIdx.x;
    const int tid = threadIdx.x;
    const int row = tokens[f];
    float v[3]; float ss = 0.f;
    #pragma unroll
    for (int i = 0; i < 3; ++i) {
        v[i] = ldin(embed, (size_t)row * DM + tid + 256 * i, f32f);
        ss += v[i] * v[i];
    }
    const float tot = block_sum(ss);
    const float rs = rsqrtf(tot * (1.f / DM) + EPSN);
    #pragma unroll
    for (int i = 0; i < 3; ++i)
        h[(size_t)f * DM + tid + 256 * i] = v[i] * rs * ldin(w, tid + 256 * i, f32f);
}

// ---- rmsnorm(h f32, w) -> bf16 ----
__global__ void rms_f2b(const float* __restrict__ h, const void* __restrict__ w, int woff,
                        u16* __restrict__ out, const int* __restrict__ flagp) {
    const int f32f = *flagp;
    const int f = blockIdx.x;
    const int tid = threadIdx.x;
    float v[3]; float ss = 0.f;
    #pragma unroll
    for (int i = 0; i < 3; ++i) { v[i] = h[(size_t)f * DM + tid + 256 * i]; ss += v[i] * v[i]; }
    const float tot = block_sum(ss);
    const float rs = rsqrtf(tot * (1.f / DM) + EPSN);
    #pragma unroll
    for (int i = 0; i < 3; ++i)
        out[(size_t)f * DM + tid + 256 * i] =
            f2b(v[i] * rs * ldin(w, woff + tid + 256 * i, f32f));
}

// ---- MFMA GEMM: C[M,N] = A[M,K](lda) * B[N,K](ldb)^T, bf16 in, f32 acc ----
// EPI: 0 = store bf16; 1 = softplus(acc+bias[n]) bf16; 3 = f32 partial to Pbuf[z][M][N]
// LDS layout [kgroup g 0..3][row][8 elems] -> wave-quarter reads 256B contiguous
// (conflict-free b128); staging writes 16B chunks.  Split-K via blockIdx.z*ksplit.
template <int EPI, int TN_>
__global__ void gemm_bt(const u16* __restrict__ A, const u16* __restrict__ Borig,
                        const u16* __restrict__ Bcv, void* __restrict__ Cv,
                        float* __restrict__ Pbuf,
                        const void* __restrict__ bias, int bias_off,
                        const int* __restrict__ flagp,
                        int M, int N, int K, int lda, int ldb, int ldc, int ksplit) {
    constexpr int NJ = TN_ / 32;          // B frags per wave
    __shared__ u16 sA[4 * 128 * 8];
    __shared__ u16 sB[4 * TN_ * 8];
    const int f32f = *flagp;
    const u16* __restrict__ B = f32f ? Bcv : Borig;
    const int tid = threadIdx.x;
    const int bm = blockIdx.x * 128;
    const int bn = blockIdx.y * TN_;
    const int lane = tid & 63, w = tid >> 6;
    const int wm = (w >> 1) * 64;
    const int wn = (w & 1) * (TN_ / 2);
    const int lr = lane & 15;
    const int g = lane >> 4;

    f32x4 acc[4][NJ];
    #pragma unroll
    for (int i = 0; i < 4; ++i)
        #pragma unroll
        for (int j = 0; j < NJ; ++j)
            acc[i][j] = (f32x4){0.f, 0.f, 0.f, 0.f};

    const int sr = tid >> 1;            // staging row (2 threads/row)
    const int g0 = (tid & 1) * 2;       // k-subgroup pair
    const int skc = g0 * 8;             // k elem offset 0 or 16

    const int kb = blockIdx.z * ksplit;
    const int ke = (kb + ksplit < K) ? (kb + ksplit) : K;

    for (int k0 = kb; k0 < ke; k0 += 32) {
        __syncthreads();
        {   // stage A tile
            uint4 v0 = {0,0,0,0}, v1 = {0,0,0,0};
            const size_t go = (size_t)(bm + sr) * lda + (k0 + skc);
            if (k0 + skc < ke)     v0 = *(const uint4*)(A + go);
            if (k0 + skc + 8 < ke) v1 = *(const uint4*)(A + go + 8);
            *(uint4*)&sA[(g0 * 128 + sr) * 8]       = v0;
            *(uint4*)&sA[((g0 + 1) * 128 + sr) * 8] = v1;
        }
        if (tid < 2 * TN_) {   // stage B tile (rows = output cols)
            uint4 v0 = {0,0,0,0}, v1 = {0,0,0,0};
            const int gn = bn + sr;
            if (gn < N) {
                const size_t go = (size_t)gn * ldb + (k0 + skc);
                if (k0 + skc < ke)     v0 = *(const uint4*)(B + go);
                if (k0 + skc + 8 < ke) v1 = *(const uint4*)(B + go + 8);
            }
            *(uint4*)&sB[(g0 * TN_ + sr) * 8]       = v0;
            *(uint4*)&sB[((g0 + 1) * TN_ + sr) * 8] = v1;
        }
        __syncthreads();

        short8_t af[4], bfr[NJ];
        #pragma unroll
        for (int i = 0; i < 4; ++i)
            af[i] = *(const short8_t*)&sA[(g * 128 + wm + i * 16 + lr) * 8];
        #pragma unroll
        for (int j = 0; j < NJ; ++j)
            bfr[j] = *(const short8_t*)&sB[(g * TN_ + wn + j * 16 + lr) * 8];
        #pragma unroll
        for (int i = 0; i < 4; ++i)
            #pragma unroll
            for (int j = 0; j < NJ; ++j)
                acc[i][j] = __builtin_amdgcn_mfma_f32_16x16x32_bf16(af[i], bfr[j], acc[i][j], 0, 0, 0);
    }

    // epilogue: C/D layout col=lane&15, row=(lane>>4)*4 + reg   [verified m89/m91]
    const int cr = (lane >> 4) * 4;
    const int cc = lane & 15;
    #pragma unroll
    for (int i = 0; i < 4; ++i) {
        const int gm0 = bm + wm + i * 16 + cr;
        #pragma unroll
        for (int j = 0; j < NJ; ++j) {
            const int gn = bn + wn + j * 16 + cc;
            if (gn < N) {
                float bval = 0.f;
                if (EPI == 1) bval = ldin(bias, (size_t)(bias_off + gn), f32f);
                #pragma unroll
                for (int r = 0; r < 4; ++r) {
                    float v = acc[i][j][r];
                    const size_t idx = (size_t)(gm0 + r) * ldc + gn;
                    if (EPI == 0) {
                        ((u16*)Cv)[idx] = f2b(v);
                    } else if (EPI == 1) {
                        v += bval;
                        v = (v > 20.f) ? v : log1pf(__expf(v));
                        ((u16*)Cv)[idx] = f2b(v);
                    } else {
                        Pbuf[(size_t)blockIdx.z * M * N + idx] = v;
                    }
                }
            }
        }
    }
}

// ---- reduce 8 x_proj split-K partials -> bf16 dbl ----
__global__ void reduce_xp(u16* __restrict__ dbl, const float* __restrict__ P) {
    const int i = blockIdx.x * 256 + threadIdx.x;
    if (i >= MPAD * DXP) return;
    float s = 0.f;
    #pragma unroll
    for (int z = 0; z < 8; ++z) s += P[(size_t)z * MPAD * DXP + i];
    dbl[i] = f2b(s);
}

// ---- reduce 2 out_proj split-K partials into residual h (f32) ----
__global__ void reduce_out(float* __restrict__ h, const float* __restrict__ P) {
    const int i = blockIdx.x * 256 + threadIdx.x;
    const int n4 = MPAD * DM / 4;
    if (i >= n4) return;
    float4 a  = ((const float4*)h)[i];
    float4 p0 = ((const float4*)P)[i];
    float4 p1 = ((const float4*)P)[i + n4];
    a.x += p0.x + p1.x; a.y += p0.y + p1.y;
    a.z += p0.z + p1.z; a.w += p0.w + p1.w;
    ((float4*)h)[i] = a;
}

// ---- causal depthwise conv(K=4) + bias + silu; fully coalesced ----
__global__ void conv_silu(const u16* __restrict__ xz, const float* __restrict__ cwT,
                          const float* __restrict__ cbF, u16* __restrict__ xc) {
    const int gid = blockIdx.x * 256 + threadIdx.x;
    if (gid >= TOTAL * (DI / 2)) return;
    const int f = gid / (DI / 2);
    const int c = (gid - f * (DI / 2)) * 2;
    int s = 0;
    while (f >= d_OFF[s + 1]) s++;
    const int t = f - d_OFF[s];

    float2 acc = *(const float2*)(cbF + c);
    #pragma unroll
    for (int j = 0; j < 4; ++j) {
        if (t - 3 + j >= 0) {
            const u32 xp = *(const u32*)(xz + (size_t)(f - 3 + j) * (2 * DI) + c);
            const float2 wv = *(const float2*)(cwT + j * DI + c);
            acc.x += __uint_as_float(xp << 16) * wv.x;
            acc.y += __uint_as_float(xp & 0xFFFF0000u) * wv.y;
        }
    }
    const float s0 = acc.x / (1.f + __expf(-acc.x));
    const float s1 = acc.y / (1.f + __expf(-acc.y));
    *(u32*)(xc + (size_t)f * DI + c) = (u32)f2b(s0) | ((u32)f2b(s1) << 16);
}

// ==================== chunk-parallel selective scan (3 passes) ====================
__global__ __launch_bounds__(256)
void scan_part1(const u16* __restrict__ xcb, const u16* __restrict__ dtb,
                const u16* __restrict__ dbl,
                const float* __restrict__ nA, int aoff,
                float* __restrict__ Pb, float* __restrict__ Sb) {
    __shared__ float sB[64 * 16];
    const int ch = blockIdx.x;
    const int g0 = ch * 64;
    const int tid = threadIdx.x;
    if (tid < 128) {
        const int t = tid >> 1, half = (tid & 1) * 8;
        uint4 q = *(const uint4*)(dbl + (size_t)(g0 + t) * DXP + DTR + half);
        float tmp[8]; unp8(q, tmp);
        *(float4*)&sB[t * 16 + half]     = *(float4*)&tmp[0];
        *(float4*)&sB[t * 16 + half + 4] = *(float4*)&tmp[4];
    }
    __syncthreads();
    const int lane = tid & 63, w = tid >> 6;
    const int c = (blockIdx.y * 4 + w) * 64 + lane;

    float A[16];
    #pragma unroll
    for (int n = 0; n < 16; ++n) A[n] = nA[aoff + n * DI + c];
    float h[16], P[16];
    #pragma unroll
    for (int n = 0; n < 16; ++n) { h[n] = 0.f; P[n] = 1.f; }

    u16 xu = xcb[(size_t)g0 * DI + c];
    u16 du = dtb[(size_t)g0 * DI + c];
    for (int t = 0; t < 64; ++t) {
        const float x = b2f(xu), dtv = b2f(du);
        if (t + 1 < 64) {
            xu = xcb[(size_t)(g0 + t + 1) * DI + c];
            du = dtb[(size_t)(g0 + t + 1) * DI + c];
        }
        float Bv[16];
        *(float4*)&Bv[0]  = *(float4*)&sB[t * 16 + 0];
        *(float4*)&Bv[4]  = *(float4*)&sB[t * 16 + 4];
        *(float4*)&Bv[8]  = *(float4*)&sB[t * 16 + 8];
        *(float4*)&Bv[12] = *(float4*)&sB[t * 16 + 12];
        const float dtx = dtv * x;
        #pragma unroll
        for (int n = 0; n < 16; ++n) {
            const float dA = __expf(dtv * A[n]);
            h[n] = dA * h[n] + dtx * Bv[n];
            P[n] *= dA;
        }
    }
    #pragma unroll
    for (int n = 0; n < 16; ++n) {
        const size_t idx = ((size_t)ch * 16 + n) * DI + c;
        Pb[idx] = P[n];
        Sb[idx] = h[n];
    }
}

__global__ __launch_bounds__(64)
void scan_part2(const float* Pb, const float* Sb, float* Hin) {
    const int bid = blockIdx.x;           // 0..191
    const int s = bid / 24, cg = bid % 24;
    const int c = cg * 64 + threadIdx.x;
    const int j0 = d_OFF[s] / 64;
    const int cnt = (d_OFF[s + 1] - d_OFF[s]) / 64;
    float h[16];
    #pragma unroll
    for (int n = 0; n < 16; ++n) h[n] = 0.f;
    for (int j = 0; j < cnt; ++j) {
        const int ch = j0 + j;
        float p[16], sv[16];
        #pragma unroll
        for (int n = 0; n < 16; ++n) {
            const size_t idx = ((size_t)ch * 16 + n) * DI + c;
            p[n] = Pb[idx]; sv[n] = Sb[idx];
        }
        #pragma unroll
        for (int n = 0; n < 16; ++n)
            Hin[((size_t)ch * 16 + n) * DI + c] = h[n];
        #pragma unroll
        for (int n = 0; n < 16; ++n)
            h[n] = p[n] * h[n] + sv[n];
    }
}

__global__ __launch_bounds__(256)
void scan_part3(const u16* __restrict__ xcb, const u16* __restrict__ dtb,
                const u16* __restrict__ xz, const u16* __restrict__ dbl,
                const float* __restrict__ nA, int aoff,
                const void* __restrict__ Dp, int doff,
                const float* __restrict__ Hin, u16* __restrict__ yb,
                const int* __restrict__ flagp) {
    __shared__ float sBC[64 * 32];
    const int f32f = *flagp;
    const int ch = blockIdx.x;
    const int g0 = ch * 64;
    const int tid = threadIdx.x;
    {
        const int t = tid >> 2, r = (tid & 3) * 8;
        uint4 q = *(const uint4*)(dbl + (size_t)(g0 + t) * DXP + DTR + r);
        float tmp[8]; unp8(q, tmp);
        *(float4*)&sBC[t * 32 + r]     = *(float4*)&tmp[0];
        *(float4*)&sBC[t * 32 + r + 4] = *(float4*)&tmp[4];
    }
    __syncthreads();
    const int lane = tid & 63, w = tid >> 6;
    const int c = (blockIdx.y * 4 + w) * 64 + lane;

    float A[16];
    #pragma unroll
    for (int n = 0; n < 16; ++n) A[n] = nA[aoff + n * DI + c];
    const float Dv = ldin(Dp, (size_t)doff + c, f32f);
    float h[16];
    #pragma unroll
    for (int n = 0; n < 16; ++n) h[n] = Hin[((size_t)ch * 16 + n) * DI + c];

    u16 xu = xcb[(size_t)g0 * DI + c];
    u16 du = dtb[(size_t)g0 * DI + c];
    u16 zu = xz[(size_t)g0 * (2 * DI) + DI + c];
    for (int t = 0; t < 64; ++t) {
        const float x = b2f(xu), dtv = b2f(du), z = b2f(zu);
        if (t + 1 < 64) {
            xu = xcb[(size_t)(g0 + t + 1) * DI + c];
            du = dtb[(size_t)(g0 + t + 1) * DI + c];
            zu = xz[(size_t)(g0 + t + 1) * (2 * DI) + DI + c];
        }
        float Bv[16], Cvv[16];
        *(float4*)&Bv[0]   = *(float4*)&sBC[t * 32 + 0];
        *(float4*)&Bv[4]   = *(float4*)&sBC[t * 32 + 4];
        *(float4*)&Bv[8]   = *(float4*)&sBC[t * 32 + 8];
        *(float4*)&Bv[12]  = *(float4*)&sBC[t * 32 + 12];
        *(float4*)&Cvv[0]  = *(float4*)&sBC[t * 32 + 16];
        *(float4*)&Cvv[4]  = *(float4*)&sBC[t * 32 + 20];
        *(float4*)&Cvv[8]  = *(float4*)&sBC[t * 32 + 24];
        *(float4*)&Cvv[12] = *(float4*)&sBC[t * 32 + 28];
        const float dtx = dtv * x;
        float acc = 0.f;
        #pragma unroll
        for (int n = 0; n < 16; ++n) {
            const float dA = __expf(dtv * A[n]);
            h[n] = dA * h[n] + dtx * Bv[n];
            acc += h[n] * Cvv[n];
        }
        const float sig = 1.f / (1.f + __expf(-z));
        yb[(size_t)(g0 + t) * DI + c] = f2b((acc + x * Dv) * (z * sig));
    }
}

// ---- final double rmsnorm -> d_out ----
__global__ void final_norm(const float* __restrict__ h, const void* __restrict__ wf,
                           const void* __restrict__ wo, void* __restrict__ out,
                           const int* __restrict__ flagp) {
    const int f32f = *flagp;
    const int f = blockIdx.x;
    const int tid = threadIdx.x;
    float v[3]; float ss = 0.f;
    #pragma unroll
    for (int i = 0; i < 3; ++i) { v[i] = h[(size_t)f * DM + tid + 256 * i]; ss += v[i] * v[i]; }
    float tot = block_sum(ss);
    float rs = rsqrtf(tot * (1.f / DM) + EPSN);
    float ss2 = 0.f;
    #pragma unroll
    for (int i = 0; i < 3; ++i) {
        v[i] = v[i] * rs * ldin(wf, tid + 256 * i, f32f);
        ss2 += v[i] * v[i];
    }
    tot = block_sum(ss2);
    rs = rsqrtf(tot * (1.f / DM) + EPSN);
    #pragma unroll
    for (int i = 0; i < 3; ++i) {
        const float r = v[i] * rs * ldin(wo, tid + 256 * i, f32f);
        const size_t idx = (size_t)f * DM + tid + 256 * i;
        if (f32f) ((float*)out)[idx] = r;
        else      ((u16*)out)[idx] = f2b(r);
    }
}

extern "C" void kernel_launch(void* const* d_in, const int* in_sizes, int n_in,
                              void* d_out, int out_size, void* d_ws, size_t ws_size,
                              hipStream_t stream) {
    const int*  tokens     = (const int*)d_in[0];
    const void* embed      = d_in[1];
    const void* in_norm_w  = d_in[2];
    const void* out_norm_w = d_in[3];
    const void* norm_w     = d_in[4];
    const void* in_proj_w  = d_in[5];
    const void* conv_w     = d_in[6];
    const void* conv_b     = d_in[7];
    const void* x_proj_w   = d_in[8];
    const void* dt_proj_w  = d_in[9];
    const void* dt_proj_b  = d_in[10];
    const void* A_log      = d_in[11];
    const void* D_param    = d_in[12];
    const void* out_proj_w = d_in[13];
    const void* norm_f_w   = d_in[14];

    char* ws = (char*)d_ws;
    float* h    = (float*)(ws);                     // MPAD*768*4  = 21,233,664
    u16* normed = (u16*)(ws + 21233664);            // MPAD*768*2  (scan: Pb/Hin alias)
    u16* xz     = (u16*)(ws + 31850496);            // MPAD*3072*2 (out_proj partials alias)
    u16* xcb    = (u16*)(ws + 74317824);            // MPAD*1536*2
    u16* dbl    = (u16*)(ws + 95551488);            // MPAD*80*2
    u16* dtb    = (u16*)(ws + 96657408);            // MPAD*1536*2 (x_proj partials alias)
    u16* yb     = (u16*)(ws + 117891072);           // MPAD*1536*2 (scan: Sb alias)
    u16* w_ip   = (u16*)(ws + 139124736);           // 2*3072*768  bf16
    u16* w_op   = (u16*)(ws + 148561920);           // 2*768*1536  bf16
    u16* w_xp   = (u16*)(ws + 153280512);           // 2*80*1536   bf16
    u16* w_dt   = (u16*)(ws + 153772032);           // 2*1536*48   bf16
    int* flag   = (int*)(ws + 154066944);
    float* cwT  = (float*)(ws + 154067200);         // 2*4*1536 f32
    float* cbF  = (float*)(ws + 154116352);         // 2*1536 f32
    float* nA   = (float*)(ws + 154128640);         // 2*16*1536 f32
    // total ~154.33 MB
    float* Pb  = (float*)normed;   // scan pass1 out / pass2 in; Hin overwrites in pass2
    float* Sb  = (float*)yb;       // scan pass1 out / pass2 in
    float* Hin = (float*)normed;
    float* Pxp = (float*)dtb;      // x_proj split-K partials (8 x 2.2 MB, dtb dead here)
    float* Pop = (float*)xz;       // out_proj split-K partials (2 x 21.2 MB, xz dead here)

    detect_dtype<<<1, 64, 0, stream>>>((const u16*)embed, flag);

    cvt_f2b<<<(2 * 2 * DI * DM + 255) / 256, 256, 0, stream>>>((const float*)in_proj_w,  w_ip, 2 * 2 * DI * DM, flag);
    cvt_f2b<<<(2 * DM * DI + 255) / 256, 256, 0, stream>>>((const float*)out_proj_w, w_op, 2 * DM * DI, flag);
    cvt_f2b<<<(2 * DXP * DI + 255) / 256, 256, 0, stream>>>((const float*)x_proj_w,  w_xp, 2 * DXP * DI, flag);
    cvt_f2b<<<(2 * DI * DTR + 255) / 256, 256, 0, stream>>>((const float*)dt_proj_w, w_dt, 2 * DI * DTR, flag);
    prep_conv<<<(2 * 16 * DI + 255) / 256, 256, 0, stream>>>(conv_w, conv_b, A_log, cwT, cbF, nA, flag);

    embed_rms<<<TOTAL, 256, 0, stream>>>(tokens, embed, in_norm_w, h, flag);

    for (int l = 0; l < 2; ++l) {
        rms_f2b<<<TOTAL, 256, 0, stream>>>(h, norm_w, l * DM, normed, flag);
        // in_proj: [MPAD,768] x [3072,768]^T -> xz
        gemm_bt<0, 128><<<dim3(MPAD / 128, 3072 / 128, 1), 256, 0, stream>>>(
            normed, (const u16*)in_proj_w + (size_t)l * 2 * DI * DM,
            w_ip + (size_t)l * 2 * DI * DM, xz, nullptr, nullptr, 0, flag,
            MPAD, 2 * DI, DM, DM, DM, 2 * DI, DM);
        conv_silu<<<(TOTAL * (DI / 2) + 255) / 256, 256, 0, stream>>>(
            xz, cwT + (size_t)l * 4 * DI, cbF + (size_t)l * DI, xcb);
        // x_proj: [MPAD,1536] x [80,1536]^T, split-K 8 -> f32 partials -> dbl bf16
        gemm_bt<3, 64><<<dim3(MPAD / 128, 2, 8), 256, 0, stream>>>(
            xcb, (const u16*)x_proj_w + (size_t)l * DXP * DI,
            w_xp + (size_t)l * DXP * DI, nullptr, Pxp, nullptr, 0, flag,
            MPAD, DXP, DI, DI, DI, DXP, DI / 8);
        reduce_xp<<<(MPAD * DXP + 255) / 256, 256, 0, stream>>>(dbl, Pxp);
        // dt_proj: [MPAD,48](lda=80) x [1536,48]^T -> softplus(+b) -> dtb
        gemm_bt<1, 128><<<dim3(MPAD / 128, DI / 128, 1), 256, 0, stream>>>(
            dbl, (const u16*)dt_proj_w + (size_t)l * DI * DTR,
            w_dt + (size_t)l * DI * DTR, dtb, nullptr, dt_proj_b, l * DI, flag,
            MPAD, DI, DTR, DXP, DTR, DI, DTR);
        // chunk-parallel selective scan
        scan_part1<<<dim3(NCHUNK, 6), 256, 0, stream>>>(
            xcb, dtb, dbl, nA, l * 16 * DI, Pb, Sb);
        scan_part2<<<NSUBJ * 24, 64, 0, stream>>>(Pb, Sb, Hin);
        scan_part3<<<dim3(NCHUNK, 6), 256, 0, stream>>>(
            xcb, dtb, xz, dbl, nA, l * 16 * DI, D_param, l * DI, Hin, yb, flag);
        // out_proj: [MPAD,1536] x [768,1536]^T, split-K 2 -> f32 partials -> h +=
        gemm_bt<3, 64><<<dim3(MPAD / 128, DM / 64, 2), 256, 0, stream>>>(
            yb, (const u16*)out_proj_w + (size_t)l * DM * DI,
            w_op + (size_t)l * DM * DI, nullptr, Pop, nullptr, 0, flag,
            MPAD, DM, DI, DI, DI, DM, DI / 2);
        reduce_out<<<(MPAD * DM / 4 + 255) / 256, 256, 0, stream>>>(h, Pop);
    }

    final_norm<<<TOTAL, 256, 0, stream>>>(h, norm_f_w, out_norm_w, d_out, flag);
}

// Round 6
// 872.302 us; speedup vs baseline: 2.5328x; 1.0237x over previous
//
#include <hip/hip_runtime.h>
#include <hip/hip_bf16.h>

typedef unsigned short u16;
typedef unsigned int u32;
typedef __attribute__((ext_vector_type(8))) short short8_t;   // 8 bf16 (4 VGPRs)
typedef __attribute__((ext_vector_type(4))) float f32x4;

// ---- static problem config ----
#define NSUBJ 8
#define TOTAL 6848
#define MPAD  6912          // 54 * 128
#define DM    768
#define DI    1536
#define DS    16
#define DTR   48
#define DXP   80            // DTR + 2*DS
#define EPSN  1e-5f
#define NCHUNK 107          // TOTAL / 64

__constant__ int d_OFF[NSUBJ + 1] = {0, 1024, 1920, 2688, 3712, 4224, 4864, 5824, 6848};

// ---- helpers ----
__device__ __forceinline__ float b2f(u16 u) {
    return __uint_as_float(((u32)u) << 16);
}
__device__ __forceinline__ u16 f2b(float f) {
    u32 u = __float_as_uint(f);
    u32 r = (u + 0x7FFFu + ((u >> 16) & 1u)) >> 16;
    return (u16)r;
}
__device__ __forceinline__ float ldin(const void* p, size_t i, int f32f) {
    return f32f ? ((const float*)p)[i] : b2f(((const u16*)p)[i]);
}
union U4 { uint4 v; u16 s[8]; };

__device__ __forceinline__ void unp8(uint4 v, float* o) {
    u32 a0 = v.x, a1 = v.y, a2 = v.z, a3 = v.w;
    o[0] = __uint_as_float(a0 << 16);  o[1] = __uint_as_float(a0 & 0xFFFF0000u);
    o[2] = __uint_as_float(a1 << 16);  o[3] = __uint_as_float(a1 & 0xFFFF0000u);
    o[4] = __uint_as_float(a2 << 16);  o[5] = __uint_as_float(a2 & 0xFFFF0000u);
    o[6] = __uint_as_float(a3 << 16);  o[7] = __uint_as_float(a3 & 0xFFFF0000u);
}

// async global -> LDS, 16B per lane; LDS dest must be wave-uniform base + lane*16
__device__ __forceinline__ void gld16(const u16* g, u16* l) {
    __builtin_amdgcn_global_load_lds(
        (const __attribute__((address_space(1))) void*)g,
        (__attribute__((address_space(3))) void*)l, 16, 0, 0);
}

__device__ __forceinline__ float block_sum(float v) {
    __shared__ float sbuf[8];
    __syncthreads();
    #pragma unroll
    for (int o = 32; o > 0; o >>= 1) v += __shfl_down(v, o, 64);
    const int lane = threadIdx.x & 63, w = threadIdx.x >> 6;
    if (lane == 0) sbuf[w] = v;
    __syncthreads();
    if (threadIdx.x == 0) sbuf[4] = sbuf[0] + sbuf[1] + sbuf[2] + sbuf[3];
    __syncthreads();
    return sbuf[4];
}

// ---- dtype detection ----
__global__ void detect_dtype(const u16* __restrict__ probe, int* __restrict__ flag) {
    const int lane = threadIdx.x;
    int cnt = 0;
    for (int i = 0; i < 32; ++i) {
        const u16 v = probe[lane * 32 + i];
        if (((v >> 7) & 0xFF) >= 0x90) cnt++;
    }
    #pragma unroll
    for (int o = 32; o > 0; o >>= 1) cnt += __shfl_down(cnt, o, 64);
    if (lane == 0) *flag = (cnt > 64) ? 1 : 0;
}

// ---- weight -> bf16 ws copy (convert if f32, plain copy if bf16) ----
__global__ void cvt_any(const void* __restrict__ src, u16* __restrict__ dst, int n,
                        const int* __restrict__ flagp) {
    const int f32f = *flagp;
    const int i = blockIdx.x * 256 + threadIdx.x;
    if (i < n) dst[i] = f32f ? f2b(((const float*)src)[i]) : ((const u16*)src)[i];
}

// ---- dt_proj weights padded K=48 -> 64 with zeros: dst[l][d][64] ----
__global__ void cvt_dtp(const void* __restrict__ src, u16* __restrict__ dst,
                        const int* __restrict__ flagp) {
    const int f32f = *flagp;
    const int i = blockIdx.x * 256 + threadIdx.x;
    if (i >= 2 * DI * 64) return;
    const int col = i & 63, row = i >> 6;
    dst[i] = (col < DTR) ? f2b(ldin(src, (size_t)row * DTR + col, f32f)) : (u16)0;
}

// ---- precompute: conv weights [l][tap][c] f32, conv bias f32, nA = -exp(A_log) [l][n][c] ----
__global__ void prep_conv(const void* __restrict__ cw, const void* __restrict__ cb,
                          const void* __restrict__ A_log,
                          float* __restrict__ cwT, float* __restrict__ cbF,
                          float* __restrict__ nA, const int* __restrict__ flagp) {
    const int f32f = *flagp;
    const int i = blockIdx.x * 256 + threadIdx.x;
    if (i < 2 * 4 * DI) {
        const int l = i / (4 * DI), r = i - l * 4 * DI;
        const int tap = r / DI, c = r - tap * DI;
        cwT[i] = ldin(cw, (size_t)l * DI * 4 + (size_t)c * 4 + tap, f32f);
    }
    if (i < 2 * DI) cbF[i] = ldin(cb, i, f32f);
    if (i < 2 * 16 * DI) {
        const int l = i / (16 * DI), r = i - l * 16 * DI;
        const int n = r / DI, c = r - n * DI;
        nA[i] = -__expf(ldin(A_log, (size_t)l * DI * DS + (size_t)c * DS + n, f32f));
    }
}

// ---- embedding gather + rmsnorm -> h f32 ----
__global__ void embed_rms(const int* __restrict__ tokens, const void* __restrict__ embed,
                          const void* __restrict__ w, float* __restrict__ h,
                          const int* __restrict__ flagp) {
    const int f32f = *flagp;
    const int f = blockIdx.x;
    const int tid = threadIdx.x;
    const int row = tokens[f];
    float v[3]; float ss = 0.f;
    #pragma unroll
    for (int i = 0; i < 3; ++i) {
        v[i] = ldin(embed, (size_t)row * DM + tid + 256 * i, f32f);
        ss += v[i] * v[i];
    }
    const float tot = block_sum(ss);
    const float rs = rsqrtf(tot * (1.f / DM) + EPSN);
    #pragma unroll
    for (int i = 0; i < 3; ++i)
        h[(size_t)f * DM + tid + 256 * i] = v[i] * rs * ldin(w, tid + 256 * i, f32f);
}

// ---- rmsnorm(h f32, w) -> bf16 ----
__global__ void rms_f2b(const float* __restrict__ h, const void* __restrict__ w, int woff,
                        u16* __restrict__ out, const int* __restrict__ flagp) {
    const int f32f = *flagp;
    const int f = blockIdx.x;
    const int tid = threadIdx.x;
    float v[3]; float ss = 0.f;
    #pragma unroll
    for (int i = 0; i < 3; ++i) { v[i] = h[(size_t)f * DM + tid + 256 * i]; ss += v[i] * v[i]; }
    const float tot = block_sum(ss);
    const float rs = rsqrtf(tot * (1.f / DM) + EPSN);
    #pragma unroll
    for (int i = 0; i < 3; ++i)
        out[(size_t)f * DM + tid + 256 * i] =
            f2b(v[i] * rs * ldin(w, woff + tid + 256 * i, f32f));
}

// ---- MFMA GEMM: C[M,N] = A[M,K](lda) * B[N,K](ldb)^T, bf16 in, f32 acc ----
// Staging via global_load_lds (16B/lane, async). LDS row-major [row][32] with
// XOR k-slot swizzle: slot s of row r holds global kpart s^(r&3); fragment for
// quarter q reads slot q^(r&3) -> bank-floor access, no padding needed.
// K (and ksplit) must be multiples of 32; no k-guards.
// EPI: 0 = store bf16; 1 = softplus(acc+bias[n]) bf16; 3 = f32 partial Pbuf[z][M][N]
template <int EPI, int TN_>
__global__ __launch_bounds__(256)
void gemm_bt(const u16* __restrict__ A, const u16* __restrict__ B,
             void* __restrict__ Cv, float* __restrict__ Pbuf,
             const void* __restrict__ bias, int bias_off,
             const int* __restrict__ flagp,
             int M, int N, int K, int lda, int ldb, int ldc, int ksplit) {
    constexpr int NJ = TN_ / 32;
    __shared__ u16 sA[128 * 32];
    __shared__ u16 sB[TN_ * 32];
    const int f32f = *flagp;
    const int tid = threadIdx.x;
    const int bm = blockIdx.x * 128;
    const int bn = blockIdx.y * TN_;
    const int lane = tid & 63, w = tid >> 6;
    const int wm = (w >> 1) * 64;
    const int wn = (w & 1) * (TN_ / 2);
    const int lr = lane & 15;
    const int q = lane >> 4;
    const int sw = (q ^ (lr & 3)) * 8;          // swizzled k-slot (u16 elems)

    // fragment LDS pointers (loop-invariant)
    const u16* pA[4]; const u16* pB[NJ];
    #pragma unroll
    for (int i = 0; i < 4; ++i) pA[i] = &sA[(wm + i * 16 + lr) * 32 + sw];
    #pragma unroll
    for (int j = 0; j < NJ; ++j) pB[j] = &sB[(wn + j * 16 + lr) * 32 + sw];

    // staging mapping: thread handles rows r0 and r0+64, swizzled kpart kp
    const int r0 = tid >> 2;
    const int kp = ((tid & 3) ^ (r0 & 3)) * 8;  // global k offset (elems)

    const u16* gA0 = A + (size_t)(bm + r0) * lda + kp;
    const u16* gA1 = A + (size_t)(bm + r0 + 64) * lda + kp;
    const u16* gB0 = B + (size_t)(bn + r0) * ldb + kp;
    const u16* gB1 = (TN_ == 128) ? (B + (size_t)(bn + r0 + 64) * ldb + kp) : nullptr;

    f32x4 acc[4][NJ];
    #pragma unroll
    for (int i = 0; i < 4; ++i)
        #pragma unroll
        for (int j = 0; j < NJ; ++j)
            acc[i][j] = (f32x4){0.f, 0.f, 0.f, 0.f};

    const int kb = blockIdx.z * ksplit;
    const int ke = (kb + ksplit < K) ? (kb + ksplit) : K;

    for (int k0 = kb; k0 < ke; k0 += 32) {
        __syncthreads();
        gld16(gA0 + k0, &sA[tid * 8]);
        gld16(gA1 + k0, &sA[(256 + tid) * 8]);
        gld16(gB0 + k0, &sB[tid * 8]);
        if constexpr (TN_ == 128) gld16(gB1 + k0, &sB[(256 + tid) * 8]);
        __syncthreads();   // drains vmcnt(0): global_load_lds complete for all waves

        short8_t af[4], bfr[NJ];
        #pragma unroll
        for (int i = 0; i < 4; ++i) af[i] = *(const short8_t*)pA[i];
        #pragma unroll
        for (int j = 0; j < NJ; ++j) bfr[j] = *(const short8_t*)pB[j];
        #pragma unroll
        for (int i = 0; i < 4; ++i)
            #pragma unroll
            for (int j = 0; j < NJ; ++j)
                acc[i][j] = __builtin_amdgcn_mfma_f32_16x16x32_bf16(af[i], bfr[j], acc[i][j], 0, 0, 0);
    }

    // epilogue: C/D layout col=lane&15, row=(lane>>4)*4 + reg   [verified m89/m91]
    const int cr = (lane >> 4) * 4;
    const int cc = lane & 15;
    #pragma unroll
    for (int i = 0; i < 4; ++i) {
        const int gm0 = bm + wm + i * 16 + cr;
        #pragma unroll
        for (int j = 0; j < NJ; ++j) {
            const int gn = bn + wn + j * 16 + cc;
            if (gn < N) {
                float bval = 0.f;
                if (EPI == 1) bval = ldin(bias, (size_t)(bias_off + gn), f32f);
                #pragma unroll
                for (int r = 0; r < 4; ++r) {
                    float v = acc[i][j][r];
                    const size_t idx = (size_t)(gm0 + r) * ldc + gn;
                    if (EPI == 0) {
                        ((u16*)Cv)[idx] = f2b(v);
                    } else if (EPI == 1) {
                        v += bval;
                        v = (v > 20.f) ? v : log1pf(__expf(v));
                        ((u16*)Cv)[idx] = f2b(v);
                    } else {
                        Pbuf[(size_t)blockIdx.z * M * N + idx] = v;
                    }
                }
            }
        }
    }
}

// ---- reduce 8 x_proj split-K partials -> bf16 dbl [MPAD,80] + padded dblp [MPAD,64] ----
__global__ void reduce_xp(u16* __restrict__ dbl, u16* __restrict__ dblp,
                          const float* __restrict__ P) {
    const int i = blockIdx.x * 256 + threadIdx.x;
    if (i >= MPAD * DXP) return;
    float s = 0.f;
    #pragma unroll
    for (int z = 0; z < 8; ++z) s += P[(size_t)z * MPAD * DXP + i];
    const u16 b = f2b(s);
    dbl[i] = b;
    const int row = i / DXP, col = i - row * DXP;
    if (col < 64) dblp[row * 64 + col] = (col < DTR) ? b : (u16)0;
}

// ---- reduce 2 out_proj split-K partials into residual h (f32) ----
__global__ void reduce_out(float* __restrict__ h, const float* __restrict__ P) {
    const int i = blockIdx.x * 256 + threadIdx.x;
    const int n4 = MPAD * DM / 4;
    if (i >= n4) return;
    float4 a  = ((const float4*)h)[i];
    float4 p0 = ((const float4*)P)[i];
    float4 p1 = ((const float4*)P)[i + n4];
    a.x += p0.x + p1.x; a.y += p0.y + p1.y;
    a.z += p0.z + p1.z; a.w += p0.w + p1.w;
    ((float4*)h)[i] = a;
}

// ---- causal depthwise conv(K=4) + bias + silu; fully coalesced ----
__global__ void conv_silu(const u16* __restrict__ xz, const float* __restrict__ cwT,
                          const float* __restrict__ cbF, u16* __restrict__ xc) {
    const int gid = blockIdx.x * 256 + threadIdx.x;
    if (gid >= TOTAL * (DI / 2)) return;
    const int f = gid / (DI / 2);
    const int c = (gid - f * (DI / 2)) * 2;
    int s = 0;
    while (f >= d_OFF[s + 1]) s++;
    const int t = f - d_OFF[s];

    float2 acc = *(const float2*)(cbF + c);
    #pragma unroll
    for (int j = 0; j < 4; ++j) {
        if (t - 3 + j >= 0) {
            const u32 xp = *(const u32*)(xz + (size_t)(f - 3 + j) * (2 * DI) + c);
            const float2 wv = *(const float2*)(cwT + j * DI + c);
            acc.x += __uint_as_float(xp << 16) * wv.x;
            acc.y += __uint_as_float(xp & 0xFFFF0000u) * wv.y;
        }
    }
    const float s0 = acc.x / (1.f + __expf(-acc.x));
    const float s1 = acc.y / (1.f + __expf(-acc.y));
    *(u32*)(xc + (size_t)f * DI + c) = (u32)f2b(s0) | ((u32)f2b(s1) << 16);
}

// ==================== chunk-parallel selective scan (3 passes) ====================
__global__ __launch_bounds__(256)
void scan_part1(const u16* __restrict__ xcb, const u16* __restrict__ dtb,
                const u16* __restrict__ dbl,
                const float* __restrict__ nA, int aoff,
                float* __restrict__ Pb, float* __restrict__ Sb) {
    __shared__ float sB[64 * 16];
    const int ch = blockIdx.x;
    const int g0 = ch * 64;
    const int tid = threadIdx.x;
    if (tid < 128) {
        const int t = tid >> 1, half = (tid & 1) * 8;
        uint4 qv = *(const uint4*)(dbl + (size_t)(g0 + t) * DXP + DTR + half);
        float tmp[8]; unp8(qv, tmp);
        *(float4*)&sB[t * 16 + half]     = *(float4*)&tmp[0];
        *(float4*)&sB[t * 16 + half + 4] = *(float4*)&tmp[4];
    }
    __syncthreads();
    const int lane = tid & 63, w = tid >> 6;
    const int c = (blockIdx.y * 4 + w) * 64 + lane;

    float A[16];
    #pragma unroll
    for (int n = 0; n < 16; ++n) A[n] = nA[aoff + n * DI + c];
    float h[16], P[16];
    #pragma unroll
    for (int n = 0; n < 16; ++n) { h[n] = 0.f; P[n] = 1.f; }

    u16 xu = xcb[(size_t)g0 * DI + c];
    u16 du = dtb[(size_t)g0 * DI + c];
    for (int t = 0; t < 64; ++t) {
        const float x = b2f(xu), dtv = b2f(du);
        if (t + 1 < 64) {
            xu = xcb[(size_t)(g0 + t + 1) * DI + c];
            du = dtb[(size_t)(g0 + t + 1) * DI + c];
        }
        float Bv[16];
        *(float4*)&Bv[0]  = *(float4*)&sB[t * 16 + 0];
        *(float4*)&Bv[4]  = *(float4*)&sB[t * 16 + 4];
        *(float4*)&Bv[8]  = *(float4*)&sB[t * 16 + 8];
        *(float4*)&Bv[12] = *(float4*)&sB[t * 16 + 12];
        const float dtx = dtv * x;
        #pragma unroll
        for (int n = 0; n < 16; ++n) {
            const float dA = __expf(dtv * A[n]);
            h[n] = dA * h[n] + dtx * Bv[n];
            P[n] *= dA;
        }
    }
    #pragma unroll
    for (int n = 0; n < 16; ++n) {
        const size_t idx = ((size_t)ch * 16 + n) * DI + c;
        Pb[idx] = P[n];
        Sb[idx] = h[n];
    }
}

__global__ __launch_bounds__(64)
void scan_part2(const float* Pb, const float* Sb, float* Hin) {
    const int bid = blockIdx.x;           // 0..191
    const int s = bid / 24, cg = bid % 24;
    const int c = cg * 64 + threadIdx.x;
    const int j0 = d_OFF[s] / 64;
    const int cnt = (d_OFF[s + 1] - d_OFF[s]) / 64;
    float h[16];
    #pragma unroll
    for (int n = 0; n < 16; ++n) h[n] = 0.f;
    for (int j = 0; j < cnt; ++j) {
        const int ch = j0 + j;
        float p[16], sv[16];
        #pragma unroll
        for (int n = 0; n < 16; ++n) {
            const size_t idx = ((size_t)ch * 16 + n) * DI + c;
            p[n] = Pb[idx]; sv[n] = Sb[idx];
        }
        #pragma unroll
        for (int n = 0; n < 16; ++n)
            Hin[((size_t)ch * 16 + n) * DI + c] = h[n];
        #pragma unroll
        for (int n = 0; n < 16; ++n)
            h[n] = p[n] * h[n] + sv[n];
    }
}

__global__ __launch_bounds__(256)
void scan_part3(const u16* __restrict__ xcb, const u16* __restrict__ dtb,
                const u16* __restrict__ xz, const u16* __restrict__ dbl,
                const float* __restrict__ nA, int aoff,
                const void* __restrict__ Dp, int doff,
                const float* __restrict__ Hin, u16* __restrict__ yb,
                const int* __restrict__ flagp) {
    __shared__ float sBC[64 * 32];
    const int f32f = *flagp;
    const int ch = blockIdx.x;
    const int g0 = ch * 64;
    const int tid = threadIdx.x;
    {
        const int t = tid >> 2, r = (tid & 3) * 8;
        uint4 qv = *(const uint4*)(dbl + (size_t)(g0 + t) * DXP + DTR + r);
        float tmp[8]; unp8(qv, tmp);
        *(float4*)&sBC[t * 32 + r]     = *(float4*)&tmp[0];
        *(float4*)&sBC[t * 32 + r + 4] = *(float4*)&tmp[4];
    }
    __syncthreads();
    const int lane = tid & 63, w = tid >> 6;
    const int c = (blockIdx.y * 4 + w) * 64 + lane;

    float A[16];
    #pragma unroll
    for (int n = 0; n < 16; ++n) A[n] = nA[aoff + n * DI + c];
    const float Dv = ldin(Dp, (size_t)doff + c, f32f);
    float h[16];
    #pragma unroll
    for (int n = 0; n < 16; ++n) h[n] = Hin[((size_t)ch * 16 + n) * DI + c];

    u16 xu = xcb[(size_t)g0 * DI + c];
    u16 du = dtb[(size_t)g0 * DI + c];
    u16 zu = xz[(size_t)g0 * (2 * DI) + DI + c];
    for (int t = 0; t < 64; ++t) {
        const float x = b2f(xu), dtv = b2f(du), z = b2f(zu);
        if (t + 1 < 64) {
            xu = xcb[(size_t)(g0 + t + 1) * DI + c];
            du = dtb[(size_t)(g0 + t + 1) * DI + c];
            zu = xz[(size_t)(g0 + t + 1) * (2 * DI) + DI + c];
        }
        float Bv[16], Cvv[16];
        *(float4*)&Bv[0]   = *(float4*)&sBC[t * 32 + 0];
        *(float4*)&Bv[4]   = *(float4*)&sBC[t * 32 + 4];
        *(float4*)&Bv[8]   = *(float4*)&sBC[t * 32 + 8];
        *(float4*)&Bv[12]  = *(float4*)&sBC[t * 32 + 12];
        *(float4*)&Cvv[0]  = *(float4*)&sBC[t * 32 + 16];
        *(float4*)&Cvv[4]  = *(float4*)&sBC[t * 32 + 20];
        *(float4*)&Cvv[8]  = *(float4*)&sBC[t * 32 + 24];
        *(float4*)&Cvv[12] = *(float4*)&sBC[t * 32 + 28];
        const float dtx = dtv * x;
        float acc = 0.f;
        #pragma unroll
        for (int n = 0; n < 16; ++n) {
            const float dA = __expf(dtv * A[n]);
            h[n] = dA * h[n] + dtx * Bv[n];
            acc += h[n] * Cvv[n];
        }
        const float sig = 1.f / (1.f + __expf(-z));
        yb[(size_t)(g0 + t) * DI + c] = f2b((acc + x * Dv) * (z * sig));
    }
}

// ---- final double rmsnorm -> d_out ----
__global__ void final_norm(const float* __restrict__ h, const void* __restrict__ wf,
                           const void* __restrict__ wo, void* __restrict__ out,
                           const int* __restrict__ flagp) {
    const int f32f = *flagp;
    const int f = blockIdx.x;
    const int tid = threadIdx.x;
    float v[3]; float ss = 0.f;
    #pragma unroll
    for (int i = 0; i < 3; ++i) { v[i] = h[(size_t)f * DM + tid + 256 * i]; ss += v[i] * v[i]; }
    float tot = block_sum(ss);
    float rs = rsqrtf(tot * (1.f / DM) + EPSN);
    float ss2 = 0.f;
    #pragma unroll
    for (int i = 0; i < 3; ++i) {
        v[i] = v[i] * rs * ldin(wf, tid + 256 * i, f32f);
        ss2 += v[i] * v[i];
    }
    tot = block_sum(ss2);
    rs = rsqrtf(tot * (1.f / DM) + EPSN);
    #pragma unroll
    for (int i = 0; i < 3; ++i) {
        const float r = v[i] * rs * ldin(wo, tid + 256 * i, f32f);
        const size_t idx = (size_t)f * DM + tid + 256 * i;
        if (f32f) ((float*)out)[idx] = r;
        else      ((u16*)out)[idx] = f2b(r);
    }
}

extern "C" void kernel_launch(void* const* d_in, const int* in_sizes, int n_in,
                              void* d_out, int out_size, void* d_ws, size_t ws_size,
                              hipStream_t stream) {
    const int*  tokens     = (const int*)d_in[0];
    const void* embed      = d_in[1];
    const void* in_norm_w  = d_in[2];
    const void* out_norm_w = d_in[3];
    const void* norm_w     = d_in[4];
    const void* in_proj_w  = d_in[5];
    const void* conv_w     = d_in[6];
    const void* conv_b     = d_in[7];
    const void* x_proj_w   = d_in[8];
    const void* dt_proj_w  = d_in[9];
    const void* dt_proj_b  = d_in[10];
    const void* A_log      = d_in[11];
    const void* D_param    = d_in[12];
    const void* out_proj_w = d_in[13];
    const void* norm_f_w   = d_in[14];

    char* ws = (char*)d_ws;
    float* h    = (float*)(ws);                     // MPAD*768*4  = 21,233,664
    u16* normed = (u16*)(ws + 21233664);            // MPAD*768*2  (aliases: dblp, Pb/Hin)
    u16* xz     = (u16*)(ws + 31850496);            // MPAD*3072*2 (out_proj partials alias)
    u16* xcb    = (u16*)(ws + 74317824);            // MPAD*1536*2
    u16* dbl    = (u16*)(ws + 95551488);            // MPAD*80*2
    u16* dtb    = (u16*)(ws + 96657408);            // MPAD*1536*2 (x_proj partials alias)
    u16* yb     = (u16*)(ws + 117891072);           // MPAD*1536*2 (scan: Sb alias)
    u16* w_ip   = (u16*)(ws + 139124736);           // 2*3072*768  bf16
    u16* w_op   = (u16*)(ws + 148561920);           // 2*768*1536  bf16
    u16* w_xp   = (u16*)(ws + 153280512);           // 2*80*1536   bf16
    u16* w_dtp  = (u16*)(ws + 153772032);           // 2*1536*64   bf16 (K padded 48->64)
    int* flag   = (int*)(ws + 154165248);
    float* cwT  = (float*)(ws + 154165504);         // 2*4*1536 f32
    float* cbF  = (float*)(ws + 154214656);         // 2*1536 f32
    float* nA   = (float*)(ws + 154226944);         // 2*16*1536 f32 -> end 154,423,552
    float* Pb  = (float*)normed;   // scan pass1 out / pass2 in; Hin overwrites in pass2
    float* Sb  = (float*)yb;       // scan pass1 out / pass2 in
    float* Hin = (float*)normed;
    u16* dblp  = (u16*)normed;     // padded dt-GEMM input (normed dead in that window)
    float* Pxp = (float*)dtb;      // x_proj split-K partials
    float* Pop = (float*)xz;       // out_proj split-K partials

    detect_dtype<<<1, 64, 0, stream>>>((const u16*)embed, flag);

    cvt_any<<<(2 * 2 * DI * DM + 255) / 256, 256, 0, stream>>>(in_proj_w,  w_ip, 2 * 2 * DI * DM, flag);
    cvt_any<<<(2 * DM * DI + 255) / 256, 256, 0, stream>>>(out_proj_w, w_op, 2 * DM * DI, flag);
    cvt_any<<<(2 * DXP * DI + 255) / 256, 256, 0, stream>>>(x_proj_w,  w_xp, 2 * DXP * DI, flag);
    cvt_dtp<<<(2 * DI * 64 + 255) / 256, 256, 0, stream>>>(dt_proj_w, w_dtp, flag);
    prep_conv<<<(2 * 16 * DI + 255) / 256, 256, 0, stream>>>(conv_w, conv_b, A_log, cwT, cbF, nA, flag);

    embed_rms<<<TOTAL, 256, 0, stream>>>(tokens, embed, in_norm_w, h, flag);

    for (int l = 0; l < 2; ++l) {
        rms_f2b<<<TOTAL, 256, 0, stream>>>(h, norm_w, l * DM, normed, flag);
        // in_proj: [MPAD,768] x [3072,768]^T -> xz
        gemm_bt<0, 128><<<dim3(MPAD / 128, 3072 / 128, 1), 256, 0, stream>>>(
            normed, w_ip + (size_t)l * 2 * DI * DM, xz, nullptr, nullptr, 0, flag,
            MPAD, 2 * DI, DM, DM, DM, 2 * DI, DM);
        conv_silu<<<(TOTAL * (DI / 2) + 255) / 256, 256, 0, stream>>>(
            xz, cwT + (size_t)l * 4 * DI, cbF + (size_t)l * DI, xcb);
        // x_proj: [MPAD,1536] x [80,1536]^T, split-K 8 -> f32 partials
        gemm_bt<3, 64><<<dim3(MPAD / 128, 2, 8), 256, 0, stream>>>(
            xcb, w_xp + (size_t)l * DXP * DI, nullptr, Pxp, nullptr, 0, flag,
            MPAD, DXP, DI, DI, DI, DXP, DI / 8);
        reduce_xp<<<(MPAD * DXP + 255) / 256, 256, 0, stream>>>(dbl, dblp, Pxp);
        // dt_proj: [MPAD,64 padded] x [1536,64 padded]^T -> softplus(+b) -> dtb
        gemm_bt<1, 128><<<dim3(MPAD / 128, DI / 128, 1), 256, 0, stream>>>(
            dblp, w_dtp + (size_t)l * DI * 64, dtb, nullptr, dt_proj_b, l * DI, flag,
            MPAD, DI, 64, 64, 64, DI, 64);
        // chunk-parallel selective scan
        scan_part1<<<dim3(NCHUNK, 6), 256, 0, stream>>>(
            xcb, dtb, dbl, nA, l * 16 * DI, Pb, Sb);
        scan_part2<<<NSUBJ * 24, 64, 0, stream>>>(Pb, Sb, Hin);
        scan_part3<<<dim3(NCHUNK, 6), 256, 0, stream>>>(
            xcb, dtb, xz, dbl, nA, l * 16 * DI, D_param, l * DI, Hin, yb, flag);
        // out_proj: [MPAD,1536] x [768,1536]^T, split-K 2 -> f32 partials -> h +=
        gemm_bt<3, 64><<<dim3(MPAD / 128, DM / 64, 2), 256, 0, stream>>>(
            yb, w_op + (size_t)l * DM * DI, nullptr, Pop, nullptr, 0, flag,
            MPAD, DM, DI, DI, DI, DM, DI / 2);
        reduce_out<<<(MPAD * DM / 4 + 255) / 256, 256, 0, stream>>>(h, Pop);
    }

    final_norm<<<TOTAL, 256, 0, stream>>>(h, norm_f_w, out_norm_w, d_out, flag);
}